// Round 2
// baseline (740.242 us; speedup 1.0000x reference)
//
#include <hip/hip_runtime.h>
#include <hip/hip_bf16.h>

typedef __attribute__((ext_vector_type(8))) short s8v;   // 8 x bf16 (4 VGPRs)
typedef __attribute__((ext_vector_type(4))) float f4v;   // 4 x f32

#define S_LEN 2048
#define NH 16
#define HD 64
#define DMODEL 1024

__device__ __forceinline__ unsigned short f2bf(float f) {
  union { float f; unsigned int u; } v; v.f = f;
  return (unsigned short)((v.u + 0x7FFFu + ((v.u >> 16) & 1u)) >> 16);
}

__device__ __forceinline__ f4v mfma16(s8v a, s8v b, f4v c) {
  return __builtin_amdgcn_mfma_f32_16x16x32_bf16(a, b, c, 0, 0, 0);
}

// ---------- transpose-cast: W[K][N] f32 -> Wt[N][K] bf16 ----------
__global__ __launch_bounds__(256)
void transpose_cast(const float* __restrict__ W, unsigned short* __restrict__ Wt,
                    int K, int N) {
  __shared__ float tile[32][33];
  int x = threadIdx.x, y = threadIdx.y;
  int n0 = blockIdx.x * 32, k0 = blockIdx.y * 32;
#pragma unroll
  for (int i = 0; i < 32; i += 8)
    tile[y + i][x] = W[(size_t)(k0 + y + i) * N + n0 + x];
  __syncthreads();
#pragma unroll
  for (int i = 0; i < 32; i += 8)
    Wt[(size_t)(n0 + y + i) * K + k0 + x] = f2bf(tile[x][y + i]);
}

// ---------- GEMM: C[M,N] = A[M,K] @ Bt[N,K]^T  (bf16 MFMA, f32 accum) ----------
// LAYOUT 0: C row-major [M,N] f32 (+bias)      -> final output (d_out is float*)
// LAYOUT 1: C as [B,H,S,HD] bf16 (n = h*64+d)  -> Q, K
// LAYOUT 2: C as [B,H,HD,S] bf16               -> V transposed
template <int LAYOUT, bool A_F32, bool BIAS>
__global__ __launch_bounds__(256, 2)
void gemm_k(const void* __restrict__ Ap, const unsigned short* __restrict__ Bt,
            void* __restrict__ Cp, const float* __restrict__ bias,
            int M, int N, int K, float scale) {
  __shared__ unsigned short As[128 * 32];
  __shared__ unsigned short Bs[128 * 32];
  const int t = threadIdx.x;
  const int l = t & 63;
  const int w = t >> 6, wr = w >> 1, wc = w & 1;
  const int m0 = blockIdx.y * 128, n0 = blockIdx.x * 128;
  const int lg = l >> 4, lm = l & 15;

  f4v acc[4][4];
#pragma unroll
  for (int i = 0; i < 4; i++)
#pragma unroll
    for (int j = 0; j < 4; j++) acc[i][j] = f4v{0.f, 0.f, 0.f, 0.f};

  const int sr = t >> 1;            // staging row 0..127
  const int c0 = (t & 1) * 16;      // staging col half

  for (int k0 = 0; k0 < K; k0 += 32) {
    // stage A tile (128 x 32)
    if (A_F32) {
      const float* A = (const float*)Ap;
      const float* src = A + (size_t)(m0 + sr) * K + k0 + c0;
      unsigned short cv[16];
#pragma unroll
      for (int i = 0; i < 4; i++) {
        f4v v = *(const f4v*)(src + i * 4);
#pragma unroll
        for (int j = 0; j < 4; j++) cv[i * 4 + j] = f2bf(v[j]);
      }
      *(s8v*)&As[sr * 32 + c0] = *(const s8v*)&cv[0];
      *(s8v*)&As[sr * 32 + c0 + 8] = *(const s8v*)&cv[8];
    } else {
      const unsigned short* A = (const unsigned short*)Ap;
      const s8v* src = (const s8v*)(A + (size_t)(m0 + sr) * K + k0 + c0);
      *(s8v*)&As[sr * 32 + c0] = src[0];
      *(s8v*)&As[sr * 32 + c0 + 8] = src[1];
    }
    // stage Bt tile (128 n-rows x 32 k)
    {
      const s8v* src = (const s8v*)(Bt + (size_t)(n0 + sr) * K + k0 + c0);
      *(s8v*)&Bs[sr * 32 + c0] = src[0];
      *(s8v*)&Bs[sr * 32 + c0 + 8] = src[1];
    }
    __syncthreads();

    s8v af[4], bf[4];
#pragma unroll
    for (int mi = 0; mi < 4; mi++)
      af[mi] = *(const s8v*)&As[(wr * 64 + mi * 16 + lm) * 32 + lg * 8];
#pragma unroll
    for (int ni = 0; ni < 4; ni++)
      bf[ni] = *(const s8v*)&Bs[(wc * 64 + ni * 16 + lm) * 32 + lg * 8];
#pragma unroll
    for (int mi = 0; mi < 4; mi++)
#pragma unroll
      for (int ni = 0; ni < 4; ni++)
        acc[mi][ni] = mfma16(af[mi], bf[ni], acc[mi][ni]);
    __syncthreads();
  }

  // epilogue
#pragma unroll
  for (int mi = 0; mi < 4; mi++)
#pragma unroll
    for (int ni = 0; ni < 4; ni++) {
      int col = n0 + wc * 64 + ni * 16 + lm;
      float bv = BIAS ? bias[col] : 0.f;
#pragma unroll
      for (int rr = 0; rr < 4; rr++) {
        int row = m0 + wr * 64 + mi * 16 + lg * 4 + rr;
        float v = acc[mi][ni][rr] * scale + bv;
        if (LAYOUT == 0) {
          ((float*)Cp)[(size_t)row * N + col] = v;
        } else {
          unsigned short h = f2bf(v);
          unsigned short* C = (unsigned short*)Cp;
          int b = row >> 11, s = row & 2047, hh = col >> 6, d = col & 63;
          if (LAYOUT == 1)
            C[(((size_t)(b * NH + hh)) * S_LEN + s) * HD + d] = h;
          else
            C[(((size_t)(b * NH + hh)) * HD + d) * S_LEN + s] = h;
        }
      }
    }
}

// ---------- flash attention (causal), Q pre-scaled by 1/8 ----------
// Q,K: [B,H,S,64] bf16    Vt: [B,H,64,S] bf16    O: [B,S,H*64] bf16
__global__ __launch_bounds__(256, 2)
void attn_k(const unsigned short* __restrict__ Q, const unsigned short* __restrict__ Km,
            const unsigned short* __restrict__ Vt, unsigned short* __restrict__ O) {
  __shared__ unsigned short pbuf[4][16 * 32];
  const int t = threadIdx.x, l = t & 63, w = t >> 6;
  const int lg = l >> 4, lm = l & 15;
  const int nqb = S_LEN / 64;  // 32 q-blocks of 64 per (b,h)
  const int bh = blockIdx.x / nqb, qb = blockIdx.x - bh * nqb;
  const int q0 = qb * 64 + w * 16;  // this wave's 16 q-rows

  const unsigned short* Qh = Q + (size_t)bh * S_LEN * HD;
  const unsigned short* Kh = Km + (size_t)bh * S_LEN * HD;
  const unsigned short* Vh = Vt + (size_t)bh * HD * S_LEN;

  s8v qf[2];
  qf[0] = *(const s8v*)(Qh + (size_t)(q0 + lm) * HD + lg * 8);
  qf[1] = *(const s8v*)(Qh + (size_t)(q0 + lm) * HD + 32 + lg * 8);

  f4v o[4];
#pragma unroll
  for (int i = 0; i < 4; i++) o[i] = f4v{0.f, 0.f, 0.f, 0.f};
  float m_[4], l_[4];
#pragma unroll
  for (int r = 0; r < 4; r++) { m_[r] = -1e30f; l_[r] = 0.f; }

  unsigned short* pb = pbuf[w];
  const int kv_end = q0 + 16;  // causal: cols < q0+16 needed

  for (int kv = 0; kv < kv_end; kv += 32) {
    f4v s0 = f4v{0.f, 0.f, 0.f, 0.f}, s1 = f4v{0.f, 0.f, 0.f, 0.f};
    s8v kf;
    kf = *(const s8v*)(Kh + (size_t)(kv + lm) * HD + lg * 8);
    s0 = mfma16(qf[0], kf, s0);
    kf = *(const s8v*)(Kh + (size_t)(kv + lm) * HD + 32 + lg * 8);
    s0 = mfma16(qf[1], kf, s0);
    kf = *(const s8v*)(Kh + (size_t)(kv + 16 + lm) * HD + lg * 8);
    s1 = mfma16(qf[0], kf, s1);
    kf = *(const s8v*)(Kh + (size_t)(kv + 16 + lm) * HD + 32 + lg * 8);
    s1 = mfma16(qf[1], kf, s1);

    if (kv + 31 > q0) {  // diagonal tile: apply causal mask
#pragma unroll
      for (int rr = 0; rr < 4; rr++) {
        int row = q0 + lg * 4 + rr;
        if (kv + lm > row) s0[rr] = -1e30f;
        if (kv + 16 + lm > row) s1[rr] = -1e30f;
      }
    }

    float al[4];
#pragma unroll
    for (int rr = 0; rr < 4; rr++) {
      float v = fmaxf(s0[rr], s1[rr]);
      v = fmaxf(v, __shfl_xor(v, 1));
      v = fmaxf(v, __shfl_xor(v, 2));
      v = fmaxf(v, __shfl_xor(v, 4));
      v = fmaxf(v, __shfl_xor(v, 8));
      float mn = fmaxf(m_[rr], v);
      al[rr] = __expf(m_[rr] - mn);
      m_[rr] = mn;
      float p0 = __expf(s0[rr] - mn);
      float p1 = __expf(s1[rr] - mn);
      float sum = p0 + p1;
      sum += __shfl_xor(sum, 1);
      sum += __shfl_xor(sum, 2);
      sum += __shfl_xor(sum, 4);
      sum += __shfl_xor(sum, 8);
      l_[rr] = l_[rr] * al[rr] + sum;
      pb[(lg * 4 + rr) * 32 + lm] = f2bf(p0);
      pb[(lg * 4 + rr) * 32 + 16 + lm] = f2bf(p1);
    }
#pragma unroll
    for (int nc = 0; nc < 4; nc++)
#pragma unroll
      for (int rr = 0; rr < 4; rr++) o[nc][rr] *= al[rr];

    // pin compiler ordering between scalar pb writes and vector pb read
    // (same-wave DS ops are in-order at HW level; this blocks reordering)
    __builtin_amdgcn_sched_barrier(0);

    // P (C-layout) -> A-frag via per-wave LDS bounce
    s8v pf = *(const s8v*)&pb[lm * 32 + lg * 8];
#pragma unroll
    for (int nc = 0; nc < 4; nc++) {
      s8v vf = *(const s8v*)(Vh + (size_t)(nc * 16 + lm) * S_LEN + kv + lg * 8);
      o[nc] = mfma16(pf, vf, o[nc]);
    }
  }

  const int b = bh >> 4, hh = bh & 15;
#pragma unroll
  for (int rr = 0; rr < 4; rr++) {
    float inv = 1.f / l_[rr];
    int qg = q0 + lg * 4 + rr;
#pragma unroll
    for (int nc = 0; nc < 4; nc++) {
      int d = nc * 16 + lm;
      O[(((size_t)b * S_LEN + qg) * NH + hh) * HD + d] = f2bf(o[nc][rr] * inv);
    }
  }
}

extern "C" void kernel_launch(void* const* d_in, const int* in_sizes, int n_in,
                              void* d_out, int out_size, void* d_ws, size_t ws_size,
                              hipStream_t stream) {
  const float* queries = (const float*)d_in[0];
  const float* keys = (const float*)d_in[1];
  const float* values = (const float*)d_in[2];
  // d_in[3] = mask: constant causal tril -> handled analytically
  const float* Wq = (const float*)d_in[4];
  const float* Wk = (const float*)d_in[5];
  const float* Wv = (const float*)d_in[6];
  const float* Wo = (const float*)d_in[7];
  const float* bo = (const float*)d_in[8];

  char* ws = (char*)d_ws;
  const size_t WB = (size_t)DMODEL * DMODEL * 2;  // 2MB per weight
  unsigned short* WqT = (unsigned short*)(ws + 0 * WB);
  unsigned short* WkT = (unsigned short*)(ws + 1 * WB);
  unsigned short* WvT = (unsigned short*)(ws + 2 * WB);
  unsigned short* WoT = (unsigned short*)(ws + 3 * WB);
  const size_t TB = (size_t)4 * S_LEN * DMODEL * 2;  // 16MB per tensor
  unsigned short* Qb = (unsigned short*)(ws + 4 * WB);
  unsigned short* Kb = (unsigned short*)(ws + 4 * WB + TB);
  unsigned short* Vtb = (unsigned short*)(ws + 4 * WB + 2 * TB);
  unsigned short* Ob = (unsigned short*)(ws + 4 * WB + 3 * TB);
  // total ws use: 8MB + 64MB = 72MB

  const int M = 4 * S_LEN;  // 8192
  dim3 tb(32, 8), tg(DMODEL / 32, DMODEL / 32);
  transpose_cast<<<tg, tb, 0, stream>>>(Wq, WqT, DMODEL, DMODEL);
  transpose_cast<<<tg, tb, 0, stream>>>(Wk, WkT, DMODEL, DMODEL);
  transpose_cast<<<tg, tb, 0, stream>>>(Wv, WvT, DMODEL, DMODEL);
  transpose_cast<<<tg, tb, 0, stream>>>(Wo, WoT, DMODEL, DMODEL);

  dim3 gg(DMODEL / 128, M / 128);  // (8, 64)
  gemm_k<1, true, false><<<gg, 256, 0, stream>>>(queries, WqT, Qb, nullptr, M, DMODEL, DMODEL, 0.125f);
  gemm_k<1, true, false><<<gg, 256, 0, stream>>>(keys, WkT, Kb, nullptr, M, DMODEL, DMODEL, 1.0f);
  gemm_k<2, true, false><<<gg, 256, 0, stream>>>(values, WvT, Vtb, nullptr, M, DMODEL, DMODEL, 1.0f);

  attn_k<<<4 * NH * (S_LEN / 64), 256, 0, stream>>>(Qb, Kb, Vtb, Ob);

  gemm_k<0, false, true><<<gg, 256, 0, stream>>>(Ob, WoT, (float*)d_out, bo, M, DMODEL, DMODEL, 1.0f);
}

// Round 3
// 396.442 us; speedup vs baseline: 1.8672x; 1.8672x over previous
//
#include <hip/hip_runtime.h>
#include <hip/hip_bf16.h>

typedef __attribute__((ext_vector_type(8))) short s8v;   // 8 x bf16 (4 VGPRs)
typedef __attribute__((ext_vector_type(4))) float f4v;   // 4 x f32

#define S_LEN 2048
#define NH 16
#define HD 64
#define DMODEL 1024
#define KVB 64

__device__ __forceinline__ unsigned short f2bf(float f) {
  union { float f; unsigned int u; } v; v.f = f;
  return (unsigned short)((v.u + 0x7FFFu + ((v.u >> 16) & 1u)) >> 16);
}

__device__ __forceinline__ f4v mfma16(s8v a, s8v b, f4v c) {
  return __builtin_amdgcn_mfma_f32_16x16x32_bf16(a, b, c, 0, 0, 0);
}

__device__ __forceinline__ void gl_lds16(const unsigned short* g, unsigned short* l) {
  __builtin_amdgcn_global_load_lds(
      (const __attribute__((address_space(1))) void*)g,
      (__attribute__((address_space(3))) void*)l, 16, 0, 0);
}

// ---------- transpose-cast: W[K][N] f32 -> Wt[N][K] bf16 ----------
__global__ __launch_bounds__(256)
void transpose_cast(const float* __restrict__ W, unsigned short* __restrict__ Wt,
                    int K, int N) {
  __shared__ float tile[32][33];
  int x = threadIdx.x, y = threadIdx.y;
  int n0 = blockIdx.x * 32, k0 = blockIdx.y * 32;
#pragma unroll
  for (int i = 0; i < 32; i += 8)
    tile[y + i][x] = W[(size_t)(k0 + y + i) * N + n0 + x];
  __syncthreads();
#pragma unroll
  for (int i = 0; i < 32; i += 8)
    Wt[(size_t)(n0 + y + i) * K + k0 + x] = f2bf(tile[x][y + i]);
}

// ---------- GEMM: C[M,N] = A[M,K] @ Bt[N,K]^T  (bf16 MFMA, f32 accum) ----------
// LAYOUT 0: C row-major [M,N] f32 (+bias)      -> final output (d_out is float*)
// LAYOUT 1: C as [B,H,S,HD] bf16 (n = h*64+d)  -> Q, K
// LAYOUT 2: C as [B,H,HD,S] bf16               -> V transposed
template <int LAYOUT, bool A_F32, bool BIAS>
__global__ __launch_bounds__(256, 2)
void gemm_k(const void* __restrict__ Ap, const unsigned short* __restrict__ Bt,
            void* __restrict__ Cp, const float* __restrict__ bias,
            int M, int N, int K, float scale) {
  __shared__ unsigned short As[128 * 32];
  __shared__ unsigned short Bs[128 * 32];
  const int t = threadIdx.x;
  const int l = t & 63;
  const int w = t >> 6, wr = w >> 1, wc = w & 1;
  const int m0 = blockIdx.y * 128, n0 = blockIdx.x * 128;
  const int lg = l >> 4, lm = l & 15;

  f4v acc[4][4];
#pragma unroll
  for (int i = 0; i < 4; i++)
#pragma unroll
    for (int j = 0; j < 4; j++) acc[i][j] = f4v{0.f, 0.f, 0.f, 0.f};

  const int sr = t >> 1;            // staging row 0..127
  const int c0 = (t & 1) * 16;      // staging col half

  for (int k0 = 0; k0 < K; k0 += 32) {
    // stage A tile (128 x 32)
    if (A_F32) {
      const float* A = (const float*)Ap;
      const float* src = A + (size_t)(m0 + sr) * K + k0 + c0;
      unsigned short cv[16];
#pragma unroll
      for (int i = 0; i < 4; i++) {
        f4v v = *(const f4v*)(src + i * 4);
#pragma unroll
        for (int j = 0; j < 4; j++) cv[i * 4 + j] = f2bf(v[j]);
      }
      *(s8v*)&As[sr * 32 + c0] = *(const s8v*)&cv[0];
      *(s8v*)&As[sr * 32 + c0 + 8] = *(const s8v*)&cv[8];
    } else {
      const unsigned short* A = (const unsigned short*)Ap;
      const s8v* src = (const s8v*)(A + (size_t)(m0 + sr) * K + k0 + c0);
      *(s8v*)&As[sr * 32 + c0] = src[0];
      *(s8v*)&As[sr * 32 + c0 + 8] = src[1];
    }
    // stage Bt tile (128 n-rows x 32 k)
    {
      const s8v* src = (const s8v*)(Bt + (size_t)(n0 + sr) * K + k0 + c0);
      *(s8v*)&Bs[sr * 32 + c0] = src[0];
      *(s8v*)&Bs[sr * 32 + c0 + 8] = src[1];
    }
    __syncthreads();

    s8v af[4], bf[4];
#pragma unroll
    for (int mi = 0; mi < 4; mi++)
      af[mi] = *(const s8v*)&As[(wr * 64 + mi * 16 + lm) * 32 + lg * 8];
#pragma unroll
    for (int ni = 0; ni < 4; ni++)
      bf[ni] = *(const s8v*)&Bs[(wc * 64 + ni * 16 + lm) * 32 + lg * 8];
#pragma unroll
    for (int mi = 0; mi < 4; mi++)
#pragma unroll
      for (int ni = 0; ni < 4; ni++)
        acc[mi][ni] = mfma16(af[mi], bf[ni], acc[mi][ni]);
    __syncthreads();
  }

  // epilogue
#pragma unroll
  for (int mi = 0; mi < 4; mi++)
#pragma unroll
    for (int ni = 0; ni < 4; ni++) {
      int col = n0 + wc * 64 + ni * 16 + lm;
      float bv = BIAS ? bias[col] : 0.f;
#pragma unroll
      for (int rr = 0; rr < 4; rr++) {
        int row = m0 + wr * 64 + mi * 16 + lg * 4 + rr;
        float v = acc[mi][ni][rr] * scale + bv;
        if (LAYOUT == 0) {
          ((float*)Cp)[(size_t)row * N + col] = v;
        } else {
          unsigned short h = f2bf(v);
          unsigned short* C = (unsigned short*)Cp;
          int b = row >> 11, s = row & 2047, hh = col >> 6, d = col & 63;
          if (LAYOUT == 1)
            C[(((size_t)(b * NH + hh)) * S_LEN + s) * HD + d] = h;
          else
            C[(((size_t)(b * NH + hh)) * HD + d) * S_LEN + s] = h;
        }
      }
    }
}

// ---------- flash attention (causal), Q pre-scaled by 1/8 ----------
// Q,K: [B,H,S,64] bf16    Vt: [B,H,64,S] bf16    O: [B,S,H*64] bf16
// Block = 64 q-rows (4 waves x 16). K/V staged in LDS (XOR-swizzled),
// double-buffered via global_load_lds; prefetch overlaps compute.
__global__ __launch_bounds__(256, 4)
void attn_k(const unsigned short* __restrict__ Q, const unsigned short* __restrict__ Km,
            const unsigned short* __restrict__ Vt, unsigned short* __restrict__ O) {
  __shared__ unsigned short Ks[2][KVB * HD];   // [kv-row][d], swizzled, 8KB each
  __shared__ unsigned short Vs[2][HD * KVB];   // [d][kv-col], swizzled, 8KB each
  __shared__ unsigned short pbuf[4][16 * KVB]; // per-wave P tile, swizzled, 2KB each
  const int t = threadIdx.x, l = t & 63, w = t >> 6;
  const int lg = l >> 4, lm = l & 15;
  const int nqb = S_LEN / 64;
  const int bh = blockIdx.x / nqb, qb = blockIdx.x - bh * nqb;
  const int q0 = qb * 64 + w * 16;  // this wave's 16 q-rows

  const unsigned short* Qh = Q + (size_t)bh * S_LEN * HD;
  const unsigned short* Kh = Km + (size_t)bh * S_LEN * HD;
  const unsigned short* Vh = Vt + (size_t)bh * HD * S_LEN;

  s8v qf[2];
  qf[0] = *(const s8v*)(Qh + (size_t)(q0 + lm) * HD + lg * 8);
  qf[1] = *(const s8v*)(Qh + (size_t)(q0 + lm) * HD + 32 + lg * 8);

  f4v o[4];
#pragma unroll
  for (int i = 0; i < 4; i++) o[i] = f4v{0.f, 0.f, 0.f, 0.f};
  float m_[4], l_[4];
#pragma unroll
  for (int r = 0; r < 4; r++) { m_[r] = -1e30f; l_[r] = 0.f; }

  // staging geometry: wave w, iter i covers rows w*8+i*32 .. +8 (128B rows).
  // LDS dest is linear (wave-uniform base + lane*16); swizzle achieved by
  // XOR-permuting the per-lane GLOBAL source chunk (same 128B row -> coalesced).
  const int sr0 = w * 8 + (l >> 3);
  const int sj = l & 7;

#define STAGE(buf, kv)                                                          \
  {                                                                             \
    _Pragma("unroll")                                                           \
    for (int i = 0; i < 2; i++) {                                               \
      int r_ = sr0 + i * 32;                                                    \
      int jj_ = ((sj ^ (r_ & 7)) << 3);                                         \
      gl_lds16(Kh + (size_t)((kv) + r_) * HD + jj_, &Ks[buf][w * 512 + i * 2048]); \
      gl_lds16(Vh + (size_t)r_ * S_LEN + (kv) + jj_, &Vs[buf][w * 512 + i * 2048]); \
    }                                                                           \
  }

  const int ntiles = qb + 1;
  int cur = 0;
  STAGE(0, 0);
  __syncthreads();

  for (int ti = 0; ti < ntiles; ++ti) {
    const int kv = ti * 64;
    if (ti + 1 < ntiles) STAGE(cur ^ 1, kv + 64);

    const unsigned short* Kb = Ks[cur];
    const unsigned short* Vb = Vs[cur];
    unsigned short* pb = pbuf[w];

    // QK^T: 4 col-subtiles of 16, K=64 in 2 slices
    f4v s[4];
#pragma unroll
    for (int sub = 0; sub < 4; sub++) {
      s[sub] = f4v{0.f, 0.f, 0.f, 0.f};
      const int r = sub * 16 + lm;
      const char* rowp = (const char*)Kb + r * 128;
      s8v k0 = *(const s8v*)(rowp + ((lg ^ (r & 7)) << 4));
      s8v k1 = *(const s8v*)(rowp + (((4 + lg) ^ (r & 7)) << 4));
      s[sub] = mfma16(qf[0], k0, s[sub]);
      s[sub] = mfma16(qf[1], k1, s[sub]);
    }

    // causal mask (diagonal tile only)
    if (kv + 63 > q0) {
#pragma unroll
      for (int sub = 0; sub < 4; sub++) {
        const int col = kv + sub * 16 + lm;
#pragma unroll
        for (int rr = 0; rr < 4; rr++) {
          const int row = q0 + lg * 4 + rr;
          if (col > row) s[sub][rr] = -1e30f;
        }
      }
    }

    // online softmax: shuffle row-max; per-lane partial row-sum (reduced at end)
    float al[4];
#pragma unroll
    for (int rr = 0; rr < 4; rr++) {
      float mx = fmaxf(fmaxf(s[0][rr], s[1][rr]), fmaxf(s[2][rr], s[3][rr]));
      mx = fmaxf(mx, __shfl_xor(mx, 1));
      mx = fmaxf(mx, __shfl_xor(mx, 2));
      mx = fmaxf(mx, __shfl_xor(mx, 4));
      mx = fmaxf(mx, __shfl_xor(mx, 8));
      float mn = fmaxf(m_[rr], mx);
      al[rr] = __expf(m_[rr] - mn);
      m_[rr] = mn;
      const int row = lg * 4 + rr;
      float psum = 0.f;
#pragma unroll
      for (int sub = 0; sub < 4; sub++) {
        float p = __expf(s[sub][rr] - mn);
        psum += p;
        const int cj = (sub * 2 + (lm >> 3)) ^ (row & 7);
        *(unsigned short*)((char*)pb + row * 128 + (cj << 4) + (lm & 7) * 2) = f2bf(p);
      }
      l_[rr] = l_[rr] * al[rr] + psum;
    }
#pragma unroll
    for (int nc = 0; nc < 4; nc++)
#pragma unroll
      for (int rr = 0; rr < 4; rr++) o[nc][rr] *= al[rr];

    // pin ordering: pbuf scalar writes above must precede vector reads below
    __builtin_amdgcn_sched_barrier(0);

    // P (A-frag): row=lm, k-cols ks*32+lg*8, same XOR swizzle
    s8v pf[2];
#pragma unroll
    for (int ks = 0; ks < 2; ks++)
      pf[ks] = *(const s8v*)((const char*)pb + lm * 128 + (((ks * 4 + lg) ^ (lm & 7)) << 4));

    // PV: o[nc] += P(16x64) @ V^T slices
#pragma unroll
    for (int nc = 0; nc < 4; nc++) {
      const int d = nc * 16 + lm;
      const char* vrow = (const char*)Vb + d * 128;
#pragma unroll
      for (int ks = 0; ks < 2; ks++) {
        s8v vf = *(const s8v*)(vrow + (((ks * 4 + lg) ^ (d & 7)) << 4));
        o[nc] = mfma16(pf[ks], vf, o[nc]);
      }
    }

    __syncthreads();  // drains vmcnt: prefetch landed; safe to swap buffers
    cur ^= 1;
  }

  // epilogue: reduce per-lane partial sums across the 16-lane row group
  const int b = bh >> 4, hh = bh & 15;
#pragma unroll
  for (int rr = 0; rr < 4; rr++) {
    float lt = l_[rr];
    lt += __shfl_xor(lt, 1);
    lt += __shfl_xor(lt, 2);
    lt += __shfl_xor(lt, 4);
    lt += __shfl_xor(lt, 8);
    float inv = 1.f / lt;
    int qg = q0 + lg * 4 + rr;
#pragma unroll
    for (int nc = 0; nc < 4; nc++) {
      int d = nc * 16 + lm;
      O[(((size_t)b * S_LEN + qg) * NH + hh) * HD + d] = f2bf(o[nc][rr] * inv);
    }
  }
#undef STAGE
}

extern "C" void kernel_launch(void* const* d_in, const int* in_sizes, int n_in,
                              void* d_out, int out_size, void* d_ws, size_t ws_size,
                              hipStream_t stream) {
  const float* queries = (const float*)d_in[0];
  const float* keys = (const float*)d_in[1];
  const float* values = (const float*)d_in[2];
  // d_in[3] = mask: constant causal tril -> handled analytically
  const float* Wq = (const float*)d_in[4];
  const float* Wk = (const float*)d_in[5];
  const float* Wv = (const float*)d_in[6];
  const float* Wo = (const float*)d_in[7];
  const float* bo = (const float*)d_in[8];

  char* ws = (char*)d_ws;
  const size_t WB = (size_t)DMODEL * DMODEL * 2;  // 2MB per weight
  unsigned short* WqT = (unsigned short*)(ws + 0 * WB);
  unsigned short* WkT = (unsigned short*)(ws + 1 * WB);
  unsigned short* WvT = (unsigned short*)(ws + 2 * WB);
  unsigned short* WoT = (unsigned short*)(ws + 3 * WB);
  const size_t TB = (size_t)4 * S_LEN * DMODEL * 2;  // 16MB per tensor
  unsigned short* Qb = (unsigned short*)(ws + 4 * WB);
  unsigned short* Kb = (unsigned short*)(ws + 4 * WB + TB);
  unsigned short* Vtb = (unsigned short*)(ws + 4 * WB + 2 * TB);
  unsigned short* Ob = (unsigned short*)(ws + 4 * WB + 3 * TB);
  // total ws use: 8MB + 64MB = 72MB

  const int M = 4 * S_LEN;  // 8192
  dim3 tb(32, 8), tg(DMODEL / 32, DMODEL / 32);
  transpose_cast<<<tg, tb, 0, stream>>>(Wq, WqT, DMODEL, DMODEL);
  transpose_cast<<<tg, tb, 0, stream>>>(Wk, WkT, DMODEL, DMODEL);
  transpose_cast<<<tg, tb, 0, stream>>>(Wv, WvT, DMODEL, DMODEL);
  transpose_cast<<<tg, tb, 0, stream>>>(Wo, WoT, DMODEL, DMODEL);

  dim3 gg(DMODEL / 128, M / 128);  // (8, 64)
  gemm_k<1, true, false><<<gg, 256, 0, stream>>>(queries, WqT, Qb, nullptr, M, DMODEL, DMODEL, 0.125f);
  gemm_k<1, true, false><<<gg, 256, 0, stream>>>(keys, WkT, Kb, nullptr, M, DMODEL, DMODEL, 1.0f);
  gemm_k<2, true, false><<<gg, 256, 0, stream>>>(values, WvT, Vtb, nullptr, M, DMODEL, DMODEL, 1.0f);

  attn_k<<<4 * NH * (S_LEN / 64), 256, 0, stream>>>(Qb, Kb, Vtb, Ob);

  gemm_k<0, false, true><<<gg, 256, 0, stream>>>(Ob, WoT, (float*)d_out, bo, M, DMODEL, DMODEL, 1.0f);
}

// Round 4
// 322.525 us; speedup vs baseline: 2.2951x; 1.2292x over previous
//
#include <hip/hip_runtime.h>
#include <hip/hip_bf16.h>

typedef __attribute__((ext_vector_type(8))) short s8v;   // 8 x bf16 (4 VGPRs)
typedef __attribute__((ext_vector_type(4))) float f4v;   // 4 x f32

#define S_LEN 2048
#define NH 16
#define HD 64
#define DMODEL 1024
#define KVB 64
#define LOG2E 1.44269504088896f

__device__ __forceinline__ unsigned short f2bf(float f) {
  union { float f; unsigned int u; } v; v.f = f;
  return (unsigned short)((v.u + 0x7FFFu + ((v.u >> 16) & 1u)) >> 16);
}

__device__ __forceinline__ f4v mfma16(s8v a, s8v b, f4v c) {
  return __builtin_amdgcn_mfma_f32_16x16x32_bf16(a, b, c, 0, 0, 0);
}

__device__ __forceinline__ void gl_lds16(const unsigned short* g, unsigned short* l) {
  __builtin_amdgcn_global_load_lds(
      (const __attribute__((address_space(1))) void*)g,
      (__attribute__((address_space(3))) void*)l, 16, 0, 0);
}

// ---------- f32 -> bf16 cast (3 tensors, grid.y selects) ----------
__global__ __launch_bounds__(256)
void cast3(const float* __restrict__ a, const float* __restrict__ b,
           const float* __restrict__ c, unsigned short* __restrict__ oa,
           unsigned short* __restrict__ ob, unsigned short* __restrict__ oc,
           int n8) {
  const float* src = (blockIdx.y == 0) ? a : (blockIdx.y == 1) ? b : c;
  unsigned short* dst = (blockIdx.y == 0) ? oa : (blockIdx.y == 1) ? ob : oc;
  for (int i = blockIdx.x * 256 + threadIdx.x; i < n8; i += gridDim.x * 256) {
    f4v v0 = *(const f4v*)(src + (size_t)i * 8);
    f4v v1 = *(const f4v*)(src + (size_t)i * 8 + 4);
    unsigned short cv[8];
#pragma unroll
    for (int j = 0; j < 4; j++) { cv[j] = f2bf(v0[j]); cv[4 + j] = f2bf(v1[j]); }
    *(s8v*)(dst + (size_t)i * 8) = *(const s8v*)cv;
  }
}

// ---------- transpose-cast: W[K][N] f32 -> Wt[N][K] bf16 ----------
__global__ __launch_bounds__(256)
void transpose_cast(const float* __restrict__ W, unsigned short* __restrict__ Wt,
                    int K, int N) {
  __shared__ float tile[32][33];
  int x = threadIdx.x, y = threadIdx.y;
  int n0 = blockIdx.x * 32, k0 = blockIdx.y * 32;
#pragma unroll
  for (int i = 0; i < 32; i += 8)
    tile[y + i][x] = W[(size_t)(k0 + y + i) * N + n0 + x];
  __syncthreads();
#pragma unroll
  for (int i = 0; i < 32; i += 8)
    Wt[(size_t)(n0 + y + i) * K + k0 + x] = f2bf(tile[x][y + i]);
}

// ---------- GEMM (m97 structure): C[M,N] = A[M,K] @ Bt[N,K]^T ----------
// A bf16 [M][K], Bt bf16 [N][K]; global_load_lds width-16 staging, BK=32.
// LAYOUT 0: C row-major [M,N] f32 (+bias)      -> final output
// LAYOUT 1: C as [B,H,S,HD] bf16 (n = h*64+d)  -> Q, K
// LAYOUT 2: C as [B,H,HD,S] bf16               -> V transposed
template <int LAYOUT, bool BIAS>
__global__ __launch_bounds__(256, 2)
void gemm_k(const unsigned short* __restrict__ A, const unsigned short* __restrict__ Bt,
            void* __restrict__ Cp, const float* __restrict__ bias,
            int M, int N, int K, float scale) {
  __shared__ unsigned short As[128 * 32];
  __shared__ unsigned short Bs[128 * 32];
  const int t = threadIdx.x;
  const int l = t & 63;
  const int w = t >> 6, wr = w >> 1, wc = w & 1;
  const int m0 = blockIdx.y * 128, n0 = blockIdx.x * 128;
  const int lg = l >> 4, lm = l & 15;

  f4v acc[4][4];
#pragma unroll
  for (int i = 0; i < 4; i++)
#pragma unroll
    for (int j = 0; j < 4; j++) acc[i][j] = f4v{0.f, 0.f, 0.f, 0.f};

  // staging: thread t covers row i*64 + (t>>2), col (t&3)*8 (16B per lane).
  // LDS dest linear: wave-uniform base (i*4096 + w*1024 bytes) + lane*16.
  const int srow = t >> 2;
  const int scol = (t & 3) * 8;
  const unsigned short* Arow = A + (size_t)(m0 + srow) * K + scol;
  const unsigned short* Brow = Bt + (size_t)(n0 + srow) * K + scol;
  unsigned short* AsW = &As[w * 512];          // +lane*8 elems implied by HW
  unsigned short* BsW = &Bs[w * 512];

  for (int k0 = 0; k0 < K; k0 += 32) {
    gl_lds16(Arow + k0, AsW);
    gl_lds16(Arow + (size_t)64 * K + k0, AsW + 2048);
    gl_lds16(Brow + k0, BsW);
    gl_lds16(Brow + (size_t)64 * K + k0, BsW + 2048);
    __syncthreads();  // compiler drains vmcnt before barrier

    s8v af[4], bf[4];
#pragma unroll
    for (int mi = 0; mi < 4; mi++)
      af[mi] = *(const s8v*)&As[(wr * 64 + mi * 16 + lm) * 32 + lg * 8];
#pragma unroll
    for (int ni = 0; ni < 4; ni++)
      bf[ni] = *(const s8v*)&Bs[(wc * 64 + ni * 16 + lm) * 32 + lg * 8];
#pragma unroll
    for (int mi = 0; mi < 4; mi++)
#pragma unroll
      for (int ni = 0; ni < 4; ni++)
        acc[mi][ni] = mfma16(af[mi], bf[ni], acc[mi][ni]);
    __syncthreads();
  }

  // epilogue
#pragma unroll
  for (int mi = 0; mi < 4; mi++)
#pragma unroll
    for (int ni = 0; ni < 4; ni++) {
      int col = n0 + wc * 64 + ni * 16 + lm;
      float bv = BIAS ? bias[col] : 0.f;
#pragma unroll
      for (int rr = 0; rr < 4; rr++) {
        int row = m0 + wr * 64 + mi * 16 + lg * 4 + rr;
        float v = acc[mi][ni][rr] * scale + bv;
        if (LAYOUT == 0) {
          ((float*)Cp)[(size_t)row * N + col] = v;
        } else {
          unsigned short h = f2bf(v);
          unsigned short* C = (unsigned short*)Cp;
          int b = row >> 11, s = row & 2047, hh = col >> 6, d = col & 63;
          if (LAYOUT == 1)
            C[(((size_t)(b * NH + hh)) * S_LEN + s) * HD + d] = h;
          else
            C[(((size_t)(b * NH + hh)) * HD + d) * S_LEN + s] = h;
        }
      }
    }
}

// ---------- flash attention (causal), Q pre-scaled by log2(e)/8 ----------
// Softmax runs in exp2 domain. Q,K: [B,H,S,64]  Vt: [B,H,64,S]  O: [B,S,H*64]
__global__ __launch_bounds__(256, 4)
void attn_k(const unsigned short* __restrict__ Q, const unsigned short* __restrict__ Km,
            const unsigned short* __restrict__ Vt, unsigned short* __restrict__ O) {
  __shared__ unsigned short Ks[2][KVB * HD];
  __shared__ unsigned short Vs[2][HD * KVB];
  __shared__ unsigned short pbuf[4][16 * KVB];
  const int t = threadIdx.x, l = t & 63, w = t >> 6;
  const int lg = l >> 4, lm = l & 15;
  const int nqb = S_LEN / 64;
  const int bh = blockIdx.x / nqb;
  const int qb = nqb - 1 - (blockIdx.x - bh * nqb);  // long blocks first (LPT)
  const int q0 = qb * 64 + w * 16;

  const unsigned short* Qh = Q + (size_t)bh * S_LEN * HD;
  const unsigned short* Kh = Km + (size_t)bh * S_LEN * HD;
  const unsigned short* Vh = Vt + (size_t)bh * HD * S_LEN;

  s8v qf[2];
  qf[0] = *(const s8v*)(Qh + (size_t)(q0 + lm) * HD + lg * 8);
  qf[1] = *(const s8v*)(Qh + (size_t)(q0 + lm) * HD + 32 + lg * 8);

  f4v o[4];
#pragma unroll
  for (int i = 0; i < 4; i++) o[i] = f4v{0.f, 0.f, 0.f, 0.f};
  float m_[4], l_[4];
#pragma unroll
  for (int r = 0; r < 4; r++) { m_[r] = -1e30f; l_[r] = 0.f; }

  const int sr0 = w * 8 + (l >> 3);
  const int sj = l & 7;

#define STAGE(buf, kv)                                                          \
  {                                                                             \
    _Pragma("unroll")                                                           \
    for (int i = 0; i < 2; i++) {                                               \
      int r_ = sr0 + i * 32;                                                    \
      int jj_ = ((sj ^ (r_ & 7)) << 3);                                         \
      gl_lds16(Kh + (size_t)((kv) + r_) * HD + jj_, &Ks[buf][w * 512 + i * 2048]); \
      gl_lds16(Vh + (size_t)r_ * S_LEN + (kv) + jj_, &Vs[buf][w * 512 + i * 2048]); \
    }                                                                           \
  }

  const int ntiles = qb + 1;
  int cur = 0;
  STAGE(0, 0);
  __syncthreads();

  for (int ti = 0; ti < ntiles; ++ti) {
    const int kv = ti * 64;
    if (ti + 1 < ntiles) STAGE(cur ^ 1, kv + 64);

    const unsigned short* Kb = Ks[cur];
    const unsigned short* Vb = Vs[cur];
    unsigned short* pb = pbuf[w];

    // QK^T (exp2-domain logits: Q pre-scaled by log2e/8)
    f4v s[4];
#pragma unroll
    for (int sub = 0; sub < 4; sub++) {
      s[sub] = f4v{0.f, 0.f, 0.f, 0.f};
      const int r = sub * 16 + lm;
      const char* rowp = (const char*)Kb + r * 128;
      s8v k0 = *(const s8v*)(rowp + ((lg ^ (r & 7)) << 4));
      s8v k1 = *(const s8v*)(rowp + (((4 + lg) ^ (r & 7)) << 4));
      s[sub] = mfma16(qf[0], k0, s[sub]);
      s[sub] = mfma16(qf[1], k1, s[sub]);
    }

    // causal mask (diagonal tile only)
    if (kv + 63 > q0) {
#pragma unroll
      for (int sub = 0; sub < 4; sub++) {
        const int col = kv + sub * 16 + lm;
#pragma unroll
        for (int rr = 0; rr < 4; rr++) {
          const int row = q0 + lg * 4 + rr;
          if (col > row) s[sub][rr] = -1e30f;
        }
      }
    }

    // tile row-max
    float mxv[4];
#pragma unroll
    for (int rr = 0; rr < 4; rr++) {
      float mx = fmaxf(fmaxf(s[0][rr], s[1][rr]), fmaxf(s[2][rr], s[3][rr]));
      mx = fmaxf(mx, __shfl_xor(mx, 1));
      mx = fmaxf(mx, __shfl_xor(mx, 2));
      mx = fmaxf(mx, __shfl_xor(mx, 4));
      mx = fmaxf(mx, __shfl_xor(mx, 8));
      mxv[rr] = mx;
    }
    // defer-max (T13): only rescale when some row grew by > 8 (exp2 domain)
    bool need = false;
#pragma unroll
    for (int rr = 0; rr < 4; rr++) need = need || (mxv[rr] > m_[rr] + 8.f);
    if (__any(need)) {
#pragma unroll
      for (int rr = 0; rr < 4; rr++) {
        float mn = fmaxf(m_[rr], mxv[rr]);
        float al = exp2f(m_[rr] - mn);
        m_[rr] = mn;
        l_[rr] *= al;
#pragma unroll
        for (int nc = 0; nc < 4; nc++) o[nc][rr] *= al;
      }
    }
    // P = exp2(s - m), store swizzled; accumulate row-sum per-lane
#pragma unroll
    for (int rr = 0; rr < 4; rr++) {
      const int row = lg * 4 + rr;
      float psum = 0.f;
#pragma unroll
      for (int sub = 0; sub < 4; sub++) {
        float p = exp2f(s[sub][rr] - m_[rr]);
        psum += p;
        const int cj = (sub * 2 + (lm >> 3)) ^ (row & 7);
        *(unsigned short*)((char*)pb + row * 128 + (cj << 4) + (lm & 7) * 2) = f2bf(p);
      }
      l_[rr] += psum;
    }

    __builtin_amdgcn_sched_barrier(0);

    s8v pf[2];
#pragma unroll
    for (int ks = 0; ks < 2; ks++)
      pf[ks] = *(const s8v*)((const char*)pb + lm * 128 + (((ks * 4 + lg) ^ (lm & 7)) << 4));

#pragma unroll
    for (int nc = 0; nc < 4; nc++) {
      const int d = nc * 16 + lm;
      const char* vrow = (const char*)Vb + d * 128;
#pragma unroll
      for (int ks = 0; ks < 2; ks++) {
        s8v vf = *(const s8v*)(vrow + (((ks * 4 + lg) ^ (d & 7)) << 4));
        o[nc] = mfma16(pf[ks], vf, o[nc]);
      }
    }

    __syncthreads();
    cur ^= 1;
  }

  const int b = bh >> 4, hh = bh & 15;
#pragma unroll
  for (int rr = 0; rr < 4; rr++) {
    float lt = l_[rr];
    lt += __shfl_xor(lt, 1);
    lt += __shfl_xor(lt, 2);
    lt += __shfl_xor(lt, 4);
    lt += __shfl_xor(lt, 8);
    float inv = 1.f / lt;
    int qg = q0 + lg * 4 + rr;
#pragma unroll
    for (int nc = 0; nc < 4; nc++) {
      int d = nc * 16 + lm;
      O[(((size_t)b * S_LEN + qg) * NH + hh) * HD + d] = f2bf(o[nc][rr] * inv);
    }
  }
#undef STAGE
}

extern "C" void kernel_launch(void* const* d_in, const int* in_sizes, int n_in,
                              void* d_out, int out_size, void* d_ws, size_t ws_size,
                              hipStream_t stream) {
  const float* queries = (const float*)d_in[0];
  const float* keys = (const float*)d_in[1];
  const float* values = (const float*)d_in[2];
  // d_in[3] = mask: constant causal tril -> handled analytically
  const float* Wq = (const float*)d_in[4];
  const float* Wk = (const float*)d_in[5];
  const float* Wv = (const float*)d_in[6];
  const float* Wo = (const float*)d_in[7];
  const float* bo = (const float*)d_in[8];

  char* ws = (char*)d_ws;
  const size_t WB = (size_t)DMODEL * DMODEL * 2;   // 2MB per weight
  unsigned short* WqT = (unsigned short*)(ws + 0 * WB);
  unsigned short* WkT = (unsigned short*)(ws + 1 * WB);
  unsigned short* WvT = (unsigned short*)(ws + 2 * WB);
  unsigned short* WoT = (unsigned short*)(ws + 3 * WB);
  const size_t TB = (size_t)4 * S_LEN * DMODEL * 2;  // 16MB per tensor
  unsigned short* Qb  = (unsigned short*)(ws + 4 * WB);
  unsigned short* Kb  = (unsigned short*)(ws + 4 * WB + TB);
  unsigned short* Vtb = (unsigned short*)(ws + 4 * WB + 2 * TB);
  unsigned short* Ob  = (unsigned short*)(ws + 4 * WB + 3 * TB);
  unsigned short* Qc  = (unsigned short*)(ws + 4 * WB + 4 * TB);  // bf16 casts
  unsigned short* Kc  = (unsigned short*)(ws + 4 * WB + 5 * TB);
  unsigned short* Vc  = (unsigned short*)(ws + 4 * WB + 6 * TB);
  // total ws use: 8MB + 112MB = 120MB

  const int M = 4 * S_LEN;  // 8192

  cast3<<<dim3(2048, 3), 256, 0, stream>>>(queries, keys, values, Qc, Kc, Vc,
                                           M * DMODEL / 8);

  dim3 tb(32, 8), tg(DMODEL / 32, DMODEL / 32);
  transpose_cast<<<tg, tb, 0, stream>>>(Wq, WqT, DMODEL, DMODEL);
  transpose_cast<<<tg, tb, 0, stream>>>(Wk, WkT, DMODEL, DMODEL);
  transpose_cast<<<tg, tb, 0, stream>>>(Wv, WvT, DMODEL, DMODEL);
  transpose_cast<<<tg, tb, 0, stream>>>(Wo, WoT, DMODEL, DMODEL);

  dim3 gg(DMODEL / 128, M / 128);  // (8, 64)
  gemm_k<1, false><<<gg, 256, 0, stream>>>(Qc, WqT, Qb, nullptr, M, DMODEL, DMODEL,
                                           0.125f * LOG2E);
  gemm_k<1, false><<<gg, 256, 0, stream>>>(Kc, WkT, Kb, nullptr, M, DMODEL, DMODEL, 1.0f);
  gemm_k<2, false><<<gg, 256, 0, stream>>>(Vc, WvT, Vtb, nullptr, M, DMODEL, DMODEL, 1.0f);

  attn_k<<<4 * NH * (S_LEN / 64), 256, 0, stream>>>(Qb, Kb, Vtb, Ob);

  gemm_k<0, true><<<gg, 256, 0, stream>>>(Ob, WoT, (float*)d_out, bo, M, DMODEL, DMODEL, 1.0f);
}

// Round 5
// 291.154 us; speedup vs baseline: 2.5424x; 1.1077x over previous
//
#include <hip/hip_runtime.h>
#include <hip/hip_bf16.h>

typedef __attribute__((ext_vector_type(8))) short s8v;   // 8 x bf16 (4 VGPRs)
typedef __attribute__((ext_vector_type(4))) short s4v;   // 4 x bf16 (2 VGPRs)
typedef __attribute__((ext_vector_type(4))) float f4v;   // 4 x f32

#define S_LEN 2048
#define NH 16
#define HD 64
#define DMODEL 1024
#define KVB 64
#define LOG2E 1.44269504088896f

__device__ __forceinline__ unsigned short f2bf(float f) {
  union { float f; unsigned int u; } v; v.f = f;
  return (unsigned short)((v.u + 0x7FFFu + ((v.u >> 16) & 1u)) >> 16);
}

__device__ __forceinline__ f4v mfma16(s8v a, s8v b, f4v c) {
  return __builtin_amdgcn_mfma_f32_16x16x32_bf16(a, b, c, 0, 0, 0);
}

__device__ __forceinline__ void gl_lds16(const unsigned short* g, unsigned short* l) {
  __builtin_amdgcn_global_load_lds(
      (const __attribute__((address_space(1))) void*)g,
      (__attribute__((address_space(3))) void*)l, 16, 0, 0);
}

// ---------- f32 -> bf16 cast (3 tensors, grid.y selects) ----------
__global__ __launch_bounds__(256)
void cast3(const float* __restrict__ a, const float* __restrict__ b,
           const float* __restrict__ c, unsigned short* __restrict__ oa,
           unsigned short* __restrict__ ob, unsigned short* __restrict__ oc,
           int n8) {
  const float* src = (blockIdx.y == 0) ? a : (blockIdx.y == 1) ? b : c;
  unsigned short* dst = (blockIdx.y == 0) ? oa : (blockIdx.y == 1) ? ob : oc;
  for (int i = blockIdx.x * 256 + threadIdx.x; i < n8; i += gridDim.x * 256) {
    f4v v0 = *(const f4v*)(src + (size_t)i * 8);
    f4v v1 = *(const f4v*)(src + (size_t)i * 8 + 4);
    unsigned short cv[8];
#pragma unroll
    for (int j = 0; j < 4; j++) { cv[j] = f2bf(v0[j]); cv[4 + j] = f2bf(v1[j]); }
    *(s8v*)(dst + (size_t)i * 8) = *(const s8v*)cv;
  }
}

// ---------- transpose-cast: W[K][N] f32 -> Wt[N][K] bf16 ----------
__global__ __launch_bounds__(256)
void transpose_cast(const float* __restrict__ W, unsigned short* __restrict__ Wt,
                    int K, int N) {
  __shared__ float tile[32][33];
  int x = threadIdx.x, y = threadIdx.y;
  int n0 = blockIdx.x * 32, k0 = blockIdx.y * 32;
#pragma unroll
  for (int i = 0; i < 32; i += 8)
    tile[y + i][x] = W[(size_t)(k0 + y + i) * N + n0 + x];
  __syncthreads();
#pragma unroll
  for (int i = 0; i < 32; i += 8)
    Wt[(size_t)(n0 + y + i) * K + k0 + x] = f2bf(tile[x][y + i]);
}

// ---------- GEMM (m97 structure): C[M,N] = A[M,K] @ Bt[N,K]^T ----------
template <int LAYOUT, bool BIAS>
__global__ __launch_bounds__(256, 2)
void gemm_k(const unsigned short* __restrict__ A, const unsigned short* __restrict__ Bt,
            void* __restrict__ Cp, const float* __restrict__ bias,
            int M, int N, int K, float scale) {
  __shared__ unsigned short As[128 * 32];
  __shared__ unsigned short Bs[128 * 32];
  const int t = threadIdx.x;
  const int l = t & 63;
  const int w = t >> 6, wr = w >> 1, wc = w & 1;
  const int m0 = blockIdx.y * 128, n0 = blockIdx.x * 128;
  const int lg = l >> 4, lm = l & 15;

  f4v acc[4][4];
#pragma unroll
  for (int i = 0; i < 4; i++)
#pragma unroll
    for (int j = 0; j < 4; j++) acc[i][j] = f4v{0.f, 0.f, 0.f, 0.f};

  const int srow = t >> 2;
  const int scol = (t & 3) * 8;
  const unsigned short* Arow = A + (size_t)(m0 + srow) * K + scol;
  const unsigned short* Brow = Bt + (size_t)(n0 + srow) * K + scol;
  unsigned short* AsW = &As[w * 512];
  unsigned short* BsW = &Bs[w * 512];

  for (int k0 = 0; k0 < K; k0 += 32) {
    gl_lds16(Arow + k0, AsW);
    gl_lds16(Arow + (size_t)64 * K + k0, AsW + 2048);
    gl_lds16(Brow + k0, BsW);
    gl_lds16(Brow + (size_t)64 * K + k0, BsW + 2048);
    __syncthreads();

    s8v af[4], bf[4];
#pragma unroll
    for (int mi = 0; mi < 4; mi++)
      af[mi] = *(const s8v*)&As[(wr * 64 + mi * 16 + lm) * 32 + lg * 8];
#pragma unroll
    for (int ni = 0; ni < 4; ni++)
      bf[ni] = *(const s8v*)&Bs[(wc * 64 + ni * 16 + lm) * 32 + lg * 8];
#pragma unroll
    for (int mi = 0; mi < 4; mi++)
#pragma unroll
      for (int ni = 0; ni < 4; ni++)
        acc[mi][ni] = mfma16(af[mi], bf[ni], acc[mi][ni]);
    __syncthreads();
  }

#pragma unroll
  for (int mi = 0; mi < 4; mi++)
#pragma unroll
    for (int ni = 0; ni < 4; ni++) {
      int col = n0 + wc * 64 + ni * 16 + lm;
      float bv = BIAS ? bias[col] : 0.f;
#pragma unroll
      for (int rr = 0; rr < 4; rr++) {
        int row = m0 + wr * 64 + mi * 16 + lg * 4 + rr;
        float v = acc[mi][ni][rr] * scale + bv;
        if (LAYOUT == 0) {
          ((float*)Cp)[(size_t)row * N + col] = v;
        } else {
          unsigned short h = f2bf(v);
          unsigned short* C = (unsigned short*)Cp;
          int b = row >> 11, s = row & 2047, hh = col >> 6, d = col & 63;
          if (LAYOUT == 1)
            C[(((size_t)(b * NH + hh)) * S_LEN + s) * HD + d] = h;
          else
            C[(((size_t)(b * NH + hh)) * HD + d) * S_LEN + s] = h;
        }
      }
    }
}

// ---------- flash attention (causal), swapped-operand QK^T ----------
// Q pre-scaled by log2(e)/8; softmax in exp2 domain, lane-local per q-row.
// Q,K: [B,H,S,64]  Vt: [B,H,64,S]  O: [B,S,H*64] bf16
__global__ __launch_bounds__(256, 4)
void attn_k(const unsigned short* __restrict__ Q, const unsigned short* __restrict__ Km,
            const unsigned short* __restrict__ Vt, unsigned short* __restrict__ O) {
  __shared__ unsigned short Ks[2][KVB * HD];
  __shared__ unsigned short Vs[2][HD * KVB];
  __shared__ unsigned short pbuf[4][16 * KVB];
  const int t = threadIdx.x, l = t & 63, w = t >> 6;
  const int lg = l >> 4, lm = l & 15;
  const int nqb = S_LEN / 64;
  const int bh = blockIdx.x / nqb, qb = blockIdx.x - bh * nqb;
  const int q0 = qb * 64 + w * 16;
  const int qrow = q0 + lm;  // this lane's q-row (swapped layout)

  const unsigned short* Qh = Q + (size_t)bh * S_LEN * HD;
  const unsigned short* Kh = Km + (size_t)bh * S_LEN * HD;
  const unsigned short* Vh = Vt + (size_t)bh * HD * S_LEN;

  // Q as B-frag: col=q=lm, contraction d=lg*8.. (same bytes as before)
  s8v qf[2];
  qf[0] = *(const s8v*)(Qh + (size_t)qrow * HD + lg * 8);
  qf[1] = *(const s8v*)(Qh + (size_t)qrow * HD + 32 + lg * 8);

  f4v o[4];  // o[nc][rr]: q=lm (col), d=nc*16+lg*4+rr (row)
#pragma unroll
  for (int i = 0; i < 4; i++) o[i] = f4v{0.f, 0.f, 0.f, 0.f};
  float m_ = -1e30f, l_ = 0.f;  // single scalar: lane-local row

  const int sr0 = w * 8 + (l >> 3);
  const int sj = l & 7;

#define STAGE(buf, kv)                                                          \
  {                                                                             \
    _Pragma("unroll")                                                           \
    for (int i = 0; i < 2; i++) {                                               \
      int r_ = sr0 + i * 32;                                                    \
      int jj_ = ((sj ^ (r_ & 7)) << 3);                                         \
      gl_lds16(Kh + (size_t)((kv) + r_) * HD + jj_, &Ks[buf][w * 512 + i * 2048]); \
      gl_lds16(Vh + (size_t)r_ * S_LEN + (kv) + jj_, &Vs[buf][w * 512 + i * 2048]); \
    }                                                                           \
  }

  const int ntiles = qb + 1;
  int cur = 0;
  STAGE(0, 0);
  __syncthreads();

  for (int ti = 0; ti < ntiles; ++ti) {
    const int kv = ti * 64;
    if (ti + 1 < ntiles) STAGE(cur ^ 1, kv + 64);

    const unsigned short* Kb = Ks[cur];
    const unsigned short* Vb = Vs[cur];
    unsigned short* pb = pbuf[w];

    // S^T = K @ Q^T : lane holds S[q=qrow][k = kv + sub*16 + lg*4 + rr]
    f4v s[4];
#pragma unroll
    for (int sub = 0; sub < 4; sub++) {
      s[sub] = f4v{0.f, 0.f, 0.f, 0.f};
      const int r = sub * 16 + lm;
      const char* rowp = (const char*)Kb + r * 128;
      s8v k0 = *(const s8v*)(rowp + ((lg ^ (r & 7)) << 4));
      s8v k1 = *(const s8v*)(rowp + (((4 + lg) ^ (r & 7)) << 4));
      s[sub] = mfma16(k0, qf[0], s[sub]);  // swapped: A=K, B=Q
      s[sub] = mfma16(k1, qf[1], s[sub]);
    }

    // causal mask (diagonal tile only)
    if (kv + 63 > q0) {
#pragma unroll
      for (int sub = 0; sub < 4; sub++) {
        const int kbase = kv + sub * 16 + lg * 4;
#pragma unroll
        for (int rr = 0; rr < 4; rr++)
          if (kbase + rr > qrow) s[sub][rr] = -1e30f;
      }
    }

    // lane-local row max (15 fmax) + 2 cross-lg shuffles
    float mx = s[0][0];
#pragma unroll
    for (int sub = 0; sub < 4; sub++)
#pragma unroll
      for (int rr = 0; rr < 4; rr++) mx = fmaxf(mx, s[sub][rr]);
    mx = fmaxf(mx, __shfl_xor(mx, 16));
    mx = fmaxf(mx, __shfl_xor(mx, 32));

    // defer-max (T13, exp2 domain, THR=8)
    if (__any(mx > m_ + 8.f)) {
      float mn = fmaxf(m_, mx);
      float al = exp2f(m_ - mn);
      m_ = mn;
      l_ *= al;
#pragma unroll
      for (int nc = 0; nc < 4; nc++)
#pragma unroll
        for (int rr = 0; rr < 4; rr++) o[nc][rr] *= al;
    }

    // P = exp2(s - m), per-lane partial row-sum; write 4x ds_write_b64
    // swizzle: 8B-quad index c=sub*4+lg stored at c ^ ((lm&7)<<1)
    float psum = 0.f;
#pragma unroll
    for (int sub = 0; sub < 4; sub++) {
      unsigned short pk[4];
#pragma unroll
      for (int rr = 0; rr < 4; rr++) {
        float p = exp2f(s[sub][rr] - m_);
        psum += p;
        pk[rr] = f2bf(p);
      }
      const int c = (sub * 4 + lg) ^ ((lm & 7) << 1);
      *(s4v*)((char*)pb + lm * 128 + (c << 3)) = *(const s4v*)pk;
    }
    l_ += psum;

    __builtin_amdgcn_sched_barrier(0);

    // P^T B-frag: col=q=lm, k=ks*32+lg*8.. ; 16B-granule swizzle (involution)
    s8v pf[2];
#pragma unroll
    for (int ks = 0; ks < 2; ks++)
      pf[ks] = *(const s8v*)((const char*)pb + lm * 128 + (((ks * 4 + lg) ^ (lm & 7)) << 4));

    // O^T += V^T @ P^T : A=V (row=d), B=P^T (col=q)
#pragma unroll
    for (int nc = 0; nc < 4; nc++) {
      const int d = nc * 16 + lm;
      const char* vrow = (const char*)Vb + d * 128;
#pragma unroll
      for (int ks = 0; ks < 2; ks++) {
        s8v vf = *(const s8v*)(vrow + (((ks * 4 + lg) ^ (d & 7)) << 4));
        o[nc] = mfma16(vf, pf[ks], o[nc]);
      }
    }

    __syncthreads();
    cur ^= 1;
  }

  // epilogue: finish row-sum across lg groups, normalize, store 8B packs
  float lt = l_;
  lt += __shfl_xor(lt, 16);
  lt += __shfl_xor(lt, 32);
  const float inv = 1.f / lt;
  const int b = bh >> 4, hh = bh & 15;
  unsigned short* Orow = O + ((size_t)b * S_LEN + qrow) * DMODEL + hh * HD;
#pragma unroll
  for (int nc = 0; nc < 4; nc++) {
    unsigned short h4[4];
#pragma unroll
    for (int rr = 0; rr < 4; rr++) h4[rr] = f2bf(o[nc][rr] * inv);
    *(s4v*)(Orow + nc * 16 + lg * 4) = *(const s4v*)h4;
  }
#undef STAGE
}

extern "C" void kernel_launch(void* const* d_in, const int* in_sizes, int n_in,
                              void* d_out, int out_size, void* d_ws, size_t ws_size,
                              hipStream_t stream) {
  const float* queries = (const float*)d_in[0];
  const float* keys = (const float*)d_in[1];
  const float* values = (const float*)d_in[2];
  // d_in[3] = mask: constant causal tril -> handled analytically
  const float* Wq = (const float*)d_in[4];
  const float* Wk = (const float*)d_in[5];
  const float* Wv = (const float*)d_in[6];
  const float* Wo = (const float*)d_in[7];
  const float* bo = (const float*)d_in[8];

  char* ws = (char*)d_ws;
  const size_t WB = (size_t)DMODEL * DMODEL * 2;   // 2MB per weight
  unsigned short* WqT = (unsigned short*)(ws + 0 * WB);
  unsigned short* WkT = (unsigned short*)(ws + 1 * WB);
  unsigned short* WvT = (unsigned short*)(ws + 2 * WB);
  unsigned short* WoT = (unsigned short*)(ws + 3 * WB);
  const size_t TB = (size_t)4 * S_LEN * DMODEL * 2;  // 16MB per tensor
  unsigned short* Qb  = (unsigned short*)(ws + 4 * WB);
  unsigned short* Kb  = (unsigned short*)(ws + 4 * WB + TB);
  unsigned short* Vtb = (unsigned short*)(ws + 4 * WB + 2 * TB);
  unsigned short* Ob  = (unsigned short*)(ws + 4 * WB + 3 * TB);
  unsigned short* Qc  = (unsigned short*)(ws + 4 * WB + 4 * TB);  // bf16 casts
  unsigned short* Kc  = (unsigned short*)(ws + 4 * WB + 5 * TB);
  unsigned short* Vc  = (unsigned short*)(ws + 4 * WB + 6 * TB);

  const int M = 4 * S_LEN;  // 8192

  cast3<<<dim3(2048, 3), 256, 0, stream>>>(queries, keys, values, Qc, Kc, Vc,
                                           M * DMODEL / 8);

  dim3 tb(32, 8), tg(DMODEL / 32, DMODEL / 32);
  transpose_cast<<<tg, tb, 0, stream>>>(Wq, WqT, DMODEL, DMODEL);
  transpose_cast<<<tg, tb, 0, stream>>>(Wk, WkT, DMODEL, DMODEL);
  transpose_cast<<<tg, tb, 0, stream>>>(Wv, WvT, DMODEL, DMODEL);
  transpose_cast<<<tg, tb, 0, stream>>>(Wo, WoT, DMODEL, DMODEL);

  dim3 gg(DMODEL / 128, M / 128);  // (8, 64)
  gemm_k<1, false><<<gg, 256, 0, stream>>>(Qc, WqT, Qb, nullptr, M, DMODEL, DMODEL,
                                           0.125f * LOG2E);
  gemm_k<1, false><<<gg, 256, 0, stream>>>(Kc, WkT, Kb, nullptr, M, DMODEL, DMODEL, 1.0f);
  gemm_k<2, false><<<gg, 256, 0, stream>>>(Vc, WvT, Vtb, nullptr, M, DMODEL, DMODEL, 1.0f);

  attn_k<<<4 * NH * (S_LEN / 64), 256, 0, stream>>>(Qb, Kb, Vtb, Ob);

  gemm_k<0, true><<<gg, 256, 0, stream>>>(Ob, WoT, (float*)d_out, bo, M, DMODEL, DMODEL, 1.0f);
}

// Round 6
// 250.944 us; speedup vs baseline: 2.9498x; 1.1602x over previous
//
#include <hip/hip_runtime.h>
#include <hip/hip_bf16.h>

typedef __attribute__((ext_vector_type(8))) short s8v;   // 8 x bf16 (4 VGPRs)
typedef __attribute__((ext_vector_type(4))) short s4v;   // 4 x bf16 (2 VGPRs)
typedef __attribute__((ext_vector_type(4))) float f4v;   // 4 x f32

#define S_LEN 2048
#define NH 16
#define HD 64
#define DMODEL 1024
#define KVB 64
#define LOG2E 1.44269504088896f

__device__ __forceinline__ unsigned short f2bf(float f) {
  union { float f; unsigned int u; } v; v.f = f;
  return (unsigned short)((v.u + 0x7FFFu + ((v.u >> 16) & 1u)) >> 16);
}

__device__ __forceinline__ f4v mfma16(s8v a, s8v b, f4v c) {
  return __builtin_amdgcn_mfma_f32_16x16x32_bf16(a, b, c, 0, 0, 0);
}

__device__ __forceinline__ void gl_lds16(const unsigned short* g, unsigned short* l) {
  __builtin_amdgcn_global_load_lds(
      (const __attribute__((address_space(1))) void*)g,
      (__attribute__((address_space(3))) void*)l, 16, 0, 0);
}

// ---------- f32 -> bf16 cast (3 tensors, grid.y selects) ----------
__global__ __launch_bounds__(256)
void cast3(const float* __restrict__ a, const float* __restrict__ b,
           const float* __restrict__ c, unsigned short* __restrict__ oa,
           unsigned short* __restrict__ ob, unsigned short* __restrict__ oc,
           int n8) {
  const float* src = (blockIdx.y == 0) ? a : (blockIdx.y == 1) ? b : c;
  unsigned short* dst = (blockIdx.y == 0) ? oa : (blockIdx.y == 1) ? ob : oc;
  for (int i = blockIdx.x * 256 + threadIdx.x; i < n8; i += gridDim.x * 256) {
    f4v v0 = *(const f4v*)(src + (size_t)i * 8);
    f4v v1 = *(const f4v*)(src + (size_t)i * 8 + 4);
    unsigned short cv[8];
#pragma unroll
    for (int j = 0; j < 4; j++) { cv[j] = f2bf(v0[j]); cv[4 + j] = f2bf(v1[j]); }
    *(s8v*)(dst + (size_t)i * 8) = *(const s8v*)cv;
  }
}

// ---------- transpose-cast: W[K][N] f32 -> Wt[N][K] bf16 ----------
__global__ __launch_bounds__(256)
void transpose_cast(const float* __restrict__ W, unsigned short* __restrict__ Wt,
                    int K, int N) {
  __shared__ float tile[32][33];
  int x = threadIdx.x, y = threadIdx.y;
  int n0 = blockIdx.x * 32, k0 = blockIdx.y * 32;
#pragma unroll
  for (int i = 0; i < 32; i += 8)
    tile[y + i][x] = W[(size_t)(k0 + y + i) * N + n0 + x];
  __syncthreads();
#pragma unroll
  for (int i = 0; i < 32; i += 8)
    Wt[(size_t)(n0 + y + i) * K + k0 + x] = f2bf(tile[x][y + i]);
}

// ---------- GEMM (m97 structure): C[M,N] = A[M,K] @ Bt[N,K]^T ----------
template <int LAYOUT, bool BIAS>
__global__ __launch_bounds__(256, 2)
void gemm_k(const unsigned short* __restrict__ A, const unsigned short* __restrict__ Bt,
            void* __restrict__ Cp, const float* __restrict__ bias,
            int M, int N, int K, float scale) {
  __shared__ unsigned short As[128 * 32];
  __shared__ unsigned short Bs[128 * 32];
  const int t = threadIdx.x;
  const int l = t & 63;
  const int w = t >> 6, wr = w >> 1, wc = w & 1;
  const int m0 = blockIdx.y * 128, n0 = blockIdx.x * 128;
  const int lg = l >> 4, lm = l & 15;

  f4v acc[4][4];
#pragma unroll
  for (int i = 0; i < 4; i++)
#pragma unroll
    for (int j = 0; j < 4; j++) acc[i][j] = f4v{0.f, 0.f, 0.f, 0.f};

  const int srow = t >> 2;
  const int scol = (t & 3) * 8;
  const unsigned short* Arow = A + (size_t)(m0 + srow) * K + scol;
  const unsigned short* Brow = Bt + (size_t)(n0 + srow) * K + scol;
  unsigned short* AsW = &As[w * 512];
  unsigned short* BsW = &Bs[w * 512];

  for (int k0 = 0; k0 < K; k0 += 32) {
    gl_lds16(Arow + k0, AsW);
    gl_lds16(Arow + (size_t)64 * K + k0, AsW + 2048);
    gl_lds16(Brow + k0, BsW);
    gl_lds16(Brow + (size_t)64 * K + k0, BsW + 2048);
    __syncthreads();

    s8v af[4], bf[4];
#pragma unroll
    for (int mi = 0; mi < 4; mi++)
      af[mi] = *(const s8v*)&As[(wr * 64 + mi * 16 + lm) * 32 + lg * 8];
#pragma unroll
    for (int ni = 0; ni < 4; ni++)
      bf[ni] = *(const s8v*)&Bs[(wc * 64 + ni * 16 + lm) * 32 + lg * 8];
#pragma unroll
    for (int mi = 0; mi < 4; mi++)
#pragma unroll
      for (int ni = 0; ni < 4; ni++)
        acc[mi][ni] = mfma16(af[mi], bf[ni], acc[mi][ni]);
    __syncthreads();
  }

#pragma unroll
  for (int mi = 0; mi < 4; mi++)
#pragma unroll
    for (int ni = 0; ni < 4; ni++) {
      int col = n0 + wc * 64 + ni * 16 + lm;
      float bv = BIAS ? bias[col] : 0.f;
#pragma unroll
      for (int rr = 0; rr < 4; rr++) {
        int row = m0 + wr * 64 + mi * 16 + lg * 4 + rr;
        float v = acc[mi][ni][rr] * scale + bv;
        if (LAYOUT == 0) {
          ((float*)Cp)[(size_t)row * N + col] = v;
        } else {
          unsigned short h = f2bf(v);
          unsigned short* C = (unsigned short*)Cp;
          int b = row >> 11, s = row & 2047, hh = col >> 6, d = col & 63;
          if (LAYOUT == 1)
            C[(((size_t)(b * NH + hh)) * S_LEN + s) * HD + d] = h;
          else
            C[(((size_t)(b * NH + hh)) * HD + d) * S_LEN + s] = h;
        }
      }
    }
}

// ---------- flash attention (causal), paired strips for uniform work ----------
// Block handles q-blocks {31-pb, pb}: short strip's KV range is a prefix of the
// long strip's -> K/V staged once, consumed by both. 1024 uniform blocks.
// Q pre-scaled by log2(e)/8; softmax in exp2 domain, lane-local per q-row.
__global__ __launch_bounds__(256, 4)
void attn_k(const unsigned short* __restrict__ Q, const unsigned short* __restrict__ Km,
            const unsigned short* __restrict__ Vt, unsigned short* __restrict__ O) {
  __shared__ unsigned short Ks[2][KVB * HD];
  __shared__ unsigned short Vs[2][HD * KVB];
  __shared__ unsigned short pbuf[4][16 * KVB];
  const int t = threadIdx.x, l = t & 63, w = t >> 6;
  const int lg = l >> 4, lm = l & 15;

  // XCD-bijective swizzle (1024 % 8 == 0): all 16 pair-blocks of a (b,h)
  // land on one XCD -> K/V panel reuse hits XCD-local L2.
  const int bid = blockIdx.x;
  const int wgid = (bid & 7) * 128 + (bid >> 3);
  const int bh = wgid >> 4, pb = wgid & 15;
  const int qbA = 31 - pb, qbB = pb;            // long strip A, short strip B
  const int q0A = qbA * 64 + w * 16, q0B = qbB * 64 + w * 16;
  const int qrA = q0A + lm, qrB = q0B + lm;

  const unsigned short* Qh = Q + (size_t)bh * S_LEN * HD;
  const unsigned short* Kh = Km + (size_t)bh * S_LEN * HD;
  const unsigned short* Vh = Vt + (size_t)bh * HD * S_LEN;

  s8v qfA[2], qfB[2];
  qfA[0] = *(const s8v*)(Qh + (size_t)qrA * HD + lg * 8);
  qfA[1] = *(const s8v*)(Qh + (size_t)qrA * HD + 32 + lg * 8);
  qfB[0] = *(const s8v*)(Qh + (size_t)qrB * HD + lg * 8);
  qfB[1] = *(const s8v*)(Qh + (size_t)qrB * HD + 32 + lg * 8);

  f4v oA[4], oB[4];
#pragma unroll
  for (int i = 0; i < 4; i++) { oA[i] = f4v{0.f, 0.f, 0.f, 0.f}; oB[i] = f4v{0.f, 0.f, 0.f, 0.f}; }
  float mA = -1e30f, lA = 0.f, mB = -1e30f, lB = 0.f;

  const int sr0 = w * 8 + (l >> 3);
  const int sj = l & 7;

#define STAGE(buf, kv)                                                          \
  {                                                                             \
    _Pragma("unroll")                                                           \
    for (int i = 0; i < 2; i++) {                                               \
      int r_ = sr0 + i * 32;                                                    \
      int jj_ = ((sj ^ (r_ & 7)) << 3);                                         \
      gl_lds16(Kh + (size_t)((kv) + r_) * HD + jj_, &Ks[buf][w * 512 + i * 2048]); \
      gl_lds16(Vh + (size_t)r_ * S_LEN + (kv) + jj_, &Vs[buf][w * 512 + i * 2048]); \
    }                                                                           \
  }

// per-strip tile compute; kf[8], Vb, pb_, kv, lg, lm in scope
#define TILE_C(QF, OO, MM, LL, QROW, ISDIAG)                                    \
  {                                                                             \
    f4v s_[4];                                                                  \
    _Pragma("unroll")                                                           \
    for (int sub = 0; sub < 4; sub++) {                                         \
      s_[sub] = f4v{0.f, 0.f, 0.f, 0.f};                                        \
      s_[sub] = mfma16(kf[sub * 2], QF[0], s_[sub]);                            \
      s_[sub] = mfma16(kf[sub * 2 + 1], QF[1], s_[sub]);                        \
    }                                                                           \
    if (ISDIAG) {                                                               \
      _Pragma("unroll")                                                         \
      for (int sub = 0; sub < 4; sub++) {                                       \
        const int kbase = kv + sub * 16 + lg * 4;                               \
        _Pragma("unroll")                                                       \
        for (int rr = 0; rr < 4; rr++)                                          \
          if (kbase + rr > (QROW)) s_[sub][rr] = -1e30f;                        \
      }                                                                         \
    }                                                                           \
    float mx = s_[0][0];                                                        \
    _Pragma("unroll")                                                           \
    for (int sub = 0; sub < 4; sub++)                                           \
      _Pragma("unroll")                                                         \
      for (int rr = 0; rr < 4; rr++) mx = fmaxf(mx, s_[sub][rr]);               \
    mx = fmaxf(mx, __shfl_xor(mx, 16));                                         \
    mx = fmaxf(mx, __shfl_xor(mx, 32));                                         \
    if (__any(mx > (MM) + 8.f)) {                                               \
      float mn = fmaxf((MM), mx);                                               \
      float al = exp2f((MM)-mn);                                                \
      (MM) = mn;                                                                \
      (LL) *= al;                                                               \
      _Pragma("unroll")                                                         \
      for (int nc = 0; nc < 4; nc++)                                            \
        _Pragma("unroll")                                                       \
        for (int rr = 0; rr < 4; rr++) OO[nc][rr] *= al;                        \
    }                                                                           \
    float psum = 0.f;                                                           \
    _Pragma("unroll")                                                           \
    for (int sub = 0; sub < 4; sub++) {                                         \
      float p0 = exp2f(s_[sub][0] - (MM));                                      \
      float p1 = exp2f(s_[sub][1] - (MM));                                      \
      float p2 = exp2f(s_[sub][2] - (MM));                                      \
      float p3 = exp2f(s_[sub][3] - (MM));                                      \
      psum += (p0 + p1) + (p2 + p3);                                            \
      unsigned int u01, u23;                                                    \
      asm("v_cvt_pk_bf16_f32 %0, %1, %2" : "=v"(u01) : "v"(p0), "v"(p1));       \
      asm("v_cvt_pk_bf16_f32 %0, %1, %2" : "=v"(u23) : "v"(p2), "v"(p3));       \
      const int c = (sub * 4 + lg) ^ ((lm & 7) << 1);                           \
      uint2 pv; pv.x = u01; pv.y = u23;                                         \
      *(uint2*)((char*)pb_ + lm * 128 + (c << 3)) = pv;                         \
    }                                                                           \
    (LL) += psum;                                                               \
    __builtin_amdgcn_sched_barrier(0);                                          \
    s8v pf0 = *(const s8v*)((const char*)pb_ + lm * 128 + ((lg ^ (lm & 7)) << 4));        \
    s8v pf1 = *(const s8v*)((const char*)pb_ + lm * 128 + (((4 + lg) ^ (lm & 7)) << 4));  \
    _Pragma("unroll")                                                           \
    for (int nc = 0; nc < 4; nc++) {                                            \
      const int d = nc * 16 + lm;                                               \
      const char* vrow = (const char*)Vb + d * 128;                             \
      s8v vf0 = *(const s8v*)(vrow + ((lg ^ (d & 7)) << 4));                    \
      s8v vf1 = *(const s8v*)(vrow + (((4 + lg) ^ (d & 7)) << 4));              \
      OO[nc] = mfma16(vf0, pf0, OO[nc]);                                        \
      OO[nc] = mfma16(vf1, pf1, OO[nc]);                                        \
    }                                                                           \
  }

  const int ntA = qbA + 1, ntB = qbB + 1;  // ntB <= ntA always
  int cur = 0;
  STAGE(0, 0);
  __syncthreads();

  for (int ti = 0; ti < ntA; ++ti) {
    const int kv = ti * 64;
    if (ti + 1 < ntA) STAGE(cur ^ 1, kv + 64);

    const unsigned short* Kb = Ks[cur];
    const unsigned short* Vb = Vs[cur];
    unsigned short* pb_ = pbuf[w];

    // K fragments: load once, shared by both strips
    s8v kf[8];
#pragma unroll
    for (int sub = 0; sub < 4; sub++) {
      const int r = sub * 16 + lm;
      const char* rowp = (const char*)Kb + r * 128;
      kf[sub * 2] = *(const s8v*)(rowp + ((lg ^ (r & 7)) << 4));
      kf[sub * 2 + 1] = *(const s8v*)(rowp + (((4 + lg) ^ (r & 7)) << 4));
    }

    TILE_C(qfA, oA, mA, lA, qrA, ti == qbA);
    if (ti < ntB) {
      __builtin_amdgcn_sched_barrier(0);  // B's pbuf writes must not pass A's reads
      TILE_C(qfB, oB, mB, lB, qrB, ti == qbB);
    }

    __syncthreads();
    cur ^= 1;
  }

  // epilogues
  const int b = bh >> 4, hh = bh & 15;
#define EPI(OO, LL, QROW)                                                       \
  {                                                                             \
    float lt = (LL);                                                            \
    lt += __shfl_xor(lt, 16);                                                   \
    lt += __shfl_xor(lt, 32);                                                   \
    const float inv = 1.f / lt;                                                 \
    unsigned short* Orow = O + ((size_t)b * S_LEN + (QROW)) * DMODEL + hh * HD; \
    _Pragma("unroll")                                                           \
    for (int nc = 0; nc < 4; nc++) {                                            \
      unsigned short h4[4];                                                     \
      _Pragma("unroll")                                                         \
      for (int rr = 0; rr < 4; rr++) h4[rr] = f2bf(OO[nc][rr] * inv);           \
      *(s4v*)(Orow + nc * 16 + lg * 4) = *(const s4v*)h4;                       \
    }                                                                           \
  }
  EPI(oA, lA, qrA);
  EPI(oB, lB, qrB);
#undef EPI
#undef TILE_C
#undef STAGE
}

extern "C" void kernel_launch(void* const* d_in, const int* in_sizes, int n_in,
                              void* d_out, int out_size, void* d_ws, size_t ws_size,
                              hipStream_t stream) {
  const float* queries = (const float*)d_in[0];
  const float* keys = (const float*)d_in[1];
  const float* values = (const float*)d_in[2];
  // d_in[3] = mask: constant causal tril -> handled analytically
  const float* Wq = (const float*)d_in[4];
  const float* Wk = (const float*)d_in[5];
  const float* Wv = (const float*)d_in[6];
  const float* Wo = (const float*)d_in[7];
  const float* bo = (const float*)d_in[8];

  char* ws = (char*)d_ws;
  const size_t WB = (size_t)DMODEL * DMODEL * 2;   // 2MB per weight
  unsigned short* WqT = (unsigned short*)(ws + 0 * WB);
  unsigned short* WkT = (unsigned short*)(ws + 1 * WB);
  unsigned short* WvT = (unsigned short*)(ws + 2 * WB);
  unsigned short* WoT = (unsigned short*)(ws + 3 * WB);
  const size_t TB = (size_t)4 * S_LEN * DMODEL * 2;  // 16MB per tensor
  unsigned short* Qb  = (unsigned short*)(ws + 4 * WB);
  unsigned short* Kb  = (unsigned short*)(ws + 4 * WB + TB);
  unsigned short* Vtb = (unsigned short*)(ws + 4 * WB + 2 * TB);
  unsigned short* Ob  = (unsigned short*)(ws + 4 * WB + 3 * TB);
  unsigned short* Qc  = (unsigned short*)(ws + 4 * WB + 4 * TB);  // bf16 casts
  unsigned short* Kc  = (unsigned short*)(ws + 4 * WB + 5 * TB);
  unsigned short* Vc  = (unsigned short*)(ws + 4 * WB + 6 * TB);

  const int M = 4 * S_LEN;  // 8192

  cast3<<<dim3(2048, 3), 256, 0, stream>>>(queries, keys, values, Qc, Kc, Vc,
                                           M * DMODEL / 8);

  dim3 tb(32, 8), tg(DMODEL / 32, DMODEL / 32);
  transpose_cast<<<tg, tb, 0, stream>>>(Wq, WqT, DMODEL, DMODEL);
  transpose_cast<<<tg, tb, 0, stream>>>(Wk, WkT, DMODEL, DMODEL);
  transpose_cast<<<tg, tb, 0, stream>>>(Wv, WvT, DMODEL, DMODEL);
  transpose_cast<<<tg, tb, 0, stream>>>(Wo, WoT, DMODEL, DMODEL);

  dim3 gg(DMODEL / 128, M / 128);  // (8, 64)
  gemm_k<1, false><<<gg, 256, 0, stream>>>(Qc, WqT, Qb, nullptr, M, DMODEL, DMODEL,
                                           0.125f * LOG2E);
  gemm_k<1, false><<<gg, 256, 0, stream>>>(Kc, WkT, Kb, nullptr, M, DMODEL, DMODEL, 1.0f);
  gemm_k<2, false><<<gg, 256, 0, stream>>>(Vc, WvT, Vtb, nullptr, M, DMODEL, DMODEL, 1.0f);

  attn_k<<<64 * 16, 256, 0, stream>>>(Qb, Kb, Vtb, Ob);

  gemm_k<0, true><<<gg, 256, 0, stream>>>(Ob, WoT, (float*)d_out, bo, M, DMODEL, DMODEL, 1.0f);
}

// Round 7
// 236.932 us; speedup vs baseline: 3.1243x; 1.0591x over previous
//
#include <hip/hip_runtime.h>
#include <hip/hip_bf16.h>

typedef __attribute__((ext_vector_type(8))) short s8v;   // 8 x bf16 (4 VGPRs)
typedef __attribute__((ext_vector_type(4))) short s4v;   // 4 x bf16 (2 VGPRs)
typedef __attribute__((ext_vector_type(4))) float f4v;   // 4 x f32

#define S_LEN 2048
#define NH 16
#define HD 64
#define DMODEL 1024
#define KVB 64
#define LOG2E 1.44269504088896f

__device__ __forceinline__ unsigned short f2bf(float f) {
  union { float f; unsigned int u; } v; v.f = f;
  return (unsigned short)((v.u + 0x7FFFu + ((v.u >> 16) & 1u)) >> 16);
}

__device__ __forceinline__ f4v mfma16(s8v a, s8v b, f4v c) {
  return __builtin_amdgcn_mfma_f32_16x16x32_bf16(a, b, c, 0, 0, 0);
}

__device__ __forceinline__ void gl_lds16(const unsigned short* g, unsigned short* l) {
  __builtin_amdgcn_global_load_lds(
      (const __attribute__((address_space(1))) void*)g,
      (__attribute__((address_space(3))) void*)l, 16, 0, 0);
}

// ---------- f32 -> bf16 cast (3 tensors, grid.y selects) ----------
__global__ __launch_bounds__(256)
void cast3(const float* __restrict__ a, const float* __restrict__ b,
           const float* __restrict__ c, unsigned short* __restrict__ oa,
           unsigned short* __restrict__ ob, unsigned short* __restrict__ oc,
           int n8) {
  const float* src = (blockIdx.y == 0) ? a : (blockIdx.y == 1) ? b : c;
  unsigned short* dst = (blockIdx.y == 0) ? oa : (blockIdx.y == 1) ? ob : oc;
  for (int i = blockIdx.x * 256 + threadIdx.x; i < n8; i += gridDim.x * 256) {
    f4v v0 = *(const f4v*)(src + (size_t)i * 8);
    f4v v1 = *(const f4v*)(src + (size_t)i * 8 + 4);
    unsigned short cv[8];
#pragma unroll
    for (int j = 0; j < 4; j++) { cv[j] = f2bf(v0[j]); cv[4 + j] = f2bf(v1[j]); }
    *(s8v*)(dst + (size_t)i * 8) = *(const s8v*)cv;
  }
}

// ---------- transpose-cast: W[K][N] f32 -> Wt[N][K] bf16 ----------
__global__ __launch_bounds__(256)
void transpose_cast(const float* __restrict__ W, unsigned short* __restrict__ Wt,
                    int K, int N) {
  __shared__ float tile[32][33];
  int x = threadIdx.x, y = threadIdx.y;
  int n0 = blockIdx.x * 32, k0 = blockIdx.y * 32;
#pragma unroll
  for (int i = 0; i < 32; i += 8)
    tile[y + i][x] = W[(size_t)(k0 + y + i) * N + n0 + x];
  __syncthreads();
#pragma unroll
  for (int i = 0; i < 32; i += 8)
    Wt[(size_t)(n0 + y + i) * K + k0 + x] = f2bf(tile[x][y + i]);
}

// ---------- GEMM (m97 structure): C[M,N] = A[M,K] @ Bt[N,K]^T ----------
template <int LAYOUT, bool BIAS>
__global__ __launch_bounds__(256, 2)
void gemm_k(const unsigned short* __restrict__ A, const unsigned short* __restrict__ Bt,
            void* __restrict__ Cp, const float* __restrict__ bias,
            int M, int N, int K, float scale) {
  __shared__ unsigned short As[128 * 32];
  __shared__ unsigned short Bs[128 * 32];
  const int t = threadIdx.x;
  const int l = t & 63;
  const int w = t >> 6, wr = w >> 1, wc = w & 1;
  const int m0 = blockIdx.y * 128, n0 = blockIdx.x * 128;
  const int lg = l >> 4, lm = l & 15;

  f4v acc[4][4];
#pragma unroll
  for (int i = 0; i < 4; i++)
#pragma unroll
    for (int j = 0; j < 4; j++) acc[i][j] = f4v{0.f, 0.f, 0.f, 0.f};

  const int srow = t >> 2;
  const int scol = (t & 3) * 8;
  const unsigned short* Arow = A + (size_t)(m0 + srow) * K + scol;
  const unsigned short* Brow = Bt + (size_t)(n0 + srow) * K + scol;
  unsigned short* AsW = &As[w * 512];
  unsigned short* BsW = &Bs[w * 512];

  for (int k0 = 0; k0 < K; k0 += 32) {
    gl_lds16(Arow + k0, AsW);
    gl_lds16(Arow + (size_t)64 * K + k0, AsW + 2048);
    gl_lds16(Brow + k0, BsW);
    gl_lds16(Brow + (size_t)64 * K + k0, BsW + 2048);
    __syncthreads();

    s8v af[4], bf[4];
#pragma unroll
    for (int mi = 0; mi < 4; mi++)
      af[mi] = *(const s8v*)&As[(wr * 64 + mi * 16 + lm) * 32 + lg * 8];
#pragma unroll
    for (int ni = 0; ni < 4; ni++)
      bf[ni] = *(const s8v*)&Bs[(wc * 64 + ni * 16 + lm) * 32 + lg * 8];
#pragma unroll
    for (int mi = 0; mi < 4; mi++)
#pragma unroll
      for (int ni = 0; ni < 4; ni++)
        acc[mi][ni] = mfma16(af[mi], bf[ni], acc[mi][ni]);
    __syncthreads();
  }

#pragma unroll
  for (int mi = 0; mi < 4; mi++)
#pragma unroll
    for (int ni = 0; ni < 4; ni++) {
      int col = n0 + wc * 64 + ni * 16 + lm;
      float bv = BIAS ? bias[col] : 0.f;
#pragma unroll
      for (int rr = 0; rr < 4; rr++) {
        int row = m0 + wr * 64 + mi * 16 + lg * 4 + rr;
        float v = acc[mi][ni][rr] * scale + bv;
        if (LAYOUT == 0) {
          ((float*)Cp)[(size_t)row * N + col] = v;
        } else {
          unsigned short h = f2bf(v);
          unsigned short* C = (unsigned short*)Cp;
          int b = row >> 11, s = row & 2047, hh = col >> 6, d = col & 63;
          if (LAYOUT == 1)
            C[(((size_t)(b * NH + hh)) * S_LEN + s) * HD + d] = h;
          else
            C[(((size_t)(b * NH + hh)) * HD + d) * S_LEN + s] = h;
        }
      }
    }
}

// ---------- flash attention (causal), 128-row paired strips ----------
// Block = strips {15-pr, pr} x 128 q-rows; 4 waves x (4 q-sets of 16 rows).
// kf/vf LDS fragments loaded ONCE per tile-step per wave, shared by 4 q-sets.
// Q pre-scaled by log2(e)/8; softmax exp2-domain, lane-local per q-row.
__global__ __launch_bounds__(256, 2)
void attn_k(const unsigned short* __restrict__ Q, const unsigned short* __restrict__ Km,
            const unsigned short* __restrict__ Vt, unsigned short* __restrict__ O) {
  __shared__ unsigned short Ks[2][KVB * HD];
  __shared__ unsigned short Vs[2][HD * KVB];
  __shared__ unsigned short pbuf[4][16 * KVB];
  const int t = threadIdx.x, l = t & 63, w = t >> 6;
  const int lg = l >> 4, lm = l & 15;

  // 512 blocks. bh = c&63 keeps same-head blocks on one XCD (c%8 = bh%8).
  // Complement pr pairing: CU's 2nd-round block (c+256) gets pr' = 7-pr ->
  // per-CU step count uniform (~50).
  const int c = blockIdx.x;
  const int bh = c & 63;
  const int pr4 = (c >> 6) & 3;
  const int pr = (c >> 8) ? 7 - pr4 : pr4;
  const int s0A = (15 - pr) * 128, s0B = pr * 128;

  const unsigned short* Qh = Q + (size_t)bh * S_LEN * HD;
  const unsigned short* Kh = Km + (size_t)bh * S_LEN * HD;
  const unsigned short* Vh = Vt + (size_t)bh * HD * S_LEN;

  // swizzle offsets collapse: every row this lane touches has (row&7)==lm&7
  const int xo0 = (lg ^ (lm & 7)) << 4;
  const int xo1 = ((4 + lg) ^ (lm & 7)) << 4;

  // 4 q-sets: {A,g0},{A,g1},{B,g0},{B,g1}; q0 = s0X + w*32 + g*16
  const int q00 = s0A + w * 32, q01 = q00 + 16;
  const int q02 = s0B + w * 32, q03 = q02 + 16;

  s8v qf0[2], qf1[2], qf2[2], qf3[2];
#define LOADQ(QF, Q0)                                                   \
  QF[0] = *(const s8v*)(Qh + (size_t)((Q0) + lm) * HD + lg * 8);        \
  QF[1] = *(const s8v*)(Qh + (size_t)((Q0) + lm) * HD + 32 + lg * 8);
  LOADQ(qf0, q00) LOADQ(qf1, q01) LOADQ(qf2, q02) LOADQ(qf3, q03)
#undef LOADQ

  f4v o0[4], o1[4], o2[4], o3[4];
#pragma unroll
  for (int i = 0; i < 4; i++) {
    o0[i] = f4v{0.f, 0.f, 0.f, 0.f}; o1[i] = f4v{0.f, 0.f, 0.f, 0.f};
    o2[i] = f4v{0.f, 0.f, 0.f, 0.f}; o3[i] = f4v{0.f, 0.f, 0.f, 0.f};
  }
  float m0_ = -1e30f, l0_ = 0.f, m1_ = -1e30f, l1_ = 0.f;
  float m2_ = -1e30f, l2_ = 0.f, m3_ = -1e30f, l3_ = 0.f;

  const int sr0 = w * 8 + (l >> 3);
  const int sj = l & 7;

#define STAGE(buf, kv)                                                          \
  {                                                                             \
    _Pragma("unroll")                                                           \
    for (int i = 0; i < 2; i++) {                                               \
      int r_ = sr0 + i * 32;                                                    \
      int jj_ = ((sj ^ (r_ & 7)) << 3);                                         \
      gl_lds16(Kh + (size_t)((kv) + r_) * HD + jj_, &Ks[buf][w * 512 + i * 2048]); \
      gl_lds16(Vh + (size_t)r_ * S_LEN + (kv) + jj_, &Vs[buf][w * 512 + i * 2048]); \
    }                                                                           \
  }

// one q-set vs current tile; kf[8], vf[8], pb_, kv, ti in scope
#define TILE_C(QF, OO, MM, LL, Q0)                                              \
  {                                                                             \
    const int dt = (Q0) >> 6;                                                   \
    if (ti <= dt) {                                                             \
      f4v s_[4];                                                                \
      _Pragma("unroll")                                                         \
      for (int sub = 0; sub < 4; sub++) {                                       \
        s_[sub] = f4v{0.f, 0.f, 0.f, 0.f};                                      \
        s_[sub] = mfma16(kf[sub * 2], QF[0], s_[sub]);                          \
        s_[sub] = mfma16(kf[sub * 2 + 1], QF[1], s_[sub]);                      \
      }                                                                         \
      if (ti == dt) {                                                           \
        const int qrow = (Q0) + lm;                                             \
        _Pragma("unroll")                                                       \
        for (int sub = 0; sub < 4; sub++) {                                     \
          const int kbase = kv + sub * 16 + lg * 4;                             \
          _Pragma("unroll")                                                     \
          for (int rr = 0; rr < 4; rr++)                                        \
            if (kbase + rr > qrow) s_[sub][rr] = -1e30f;                        \
        }                                                                       \
      }                                                                         \
      float mx = s_[0][0];                                                      \
      _Pragma("unroll")                                                         \
      for (int sub = 0; sub < 4; sub++)                                         \
        _Pragma("unroll")                                                       \
        for (int rr = 0; rr < 4; rr++) mx = fmaxf(mx, s_[sub][rr]);             \
      mx = fmaxf(mx, __shfl_xor(mx, 16));                                       \
      mx = fmaxf(mx, __shfl_xor(mx, 32));                                       \
      if (__any(mx > (MM) + 8.f)) {                                             \
        float mn = fmaxf((MM), mx);                                             \
        float al = exp2f((MM)-mn);                                              \
        (MM) = mn;                                                              \
        (LL) *= al;                                                             \
        _Pragma("unroll")                                                       \
        for (int nc = 0; nc < 4; nc++)                                          \
          _Pragma("unroll")                                                     \
          for (int rr = 0; rr < 4; rr++) OO[nc][rr] *= al;                      \
      }                                                                         \
      float psum = 0.f;                                                         \
      _Pragma("unroll")                                                         \
      for (int sub = 0; sub < 4; sub++) {                                       \
        float p0 = exp2f(s_[sub][0] - (MM));                                    \
        float p1 = exp2f(s_[sub][1] - (MM));                                    \
        float p2 = exp2f(s_[sub][2] - (MM));                                    \
        float p3 = exp2f(s_[sub][3] - (MM));                                    \
        psum += (p0 + p1) + (p2 + p3);                                          \
        unsigned int u01, u23;                                                  \
        asm("v_cvt_pk_bf16_f32 %0, %1, %2" : "=v"(u01) : "v"(p0), "v"(p1));     \
        asm("v_cvt_pk_bf16_f32 %0, %1, %2" : "=v"(u23) : "v"(p2), "v"(p3));     \
        const int cc = (sub * 4 + lg) ^ ((lm & 7) << 1);                        \
        uint2 pv; pv.x = u01; pv.y = u23;                                       \
        *(uint2*)((char*)pb_ + lm * 128 + (cc << 3)) = pv;                      \
      }                                                                         \
      (LL) += psum;                                                             \
      __builtin_amdgcn_sched_barrier(0);                                        \
      s8v pf0 = *(const s8v*)((const char*)pb_ + lm * 128 + xo0);               \
      s8v pf1 = *(const s8v*)((const char*)pb_ + lm * 128 + xo1);               \
      _Pragma("unroll")                                                         \
      for (int nc = 0; nc < 4; nc++) {                                          \
        OO[nc] = mfma16(vf[nc * 2], pf0, OO[nc]);                               \
        OO[nc] = mfma16(vf[nc * 2 + 1], pf1, OO[nc]);                           \
      }                                                                         \
    }                                                                           \
  }

  const int nt = 2 * (15 - pr) + 2;  // strip-A tile count (always the longer)
  int cur = 0;
  STAGE(0, 0);
  __syncthreads();

  for (int ti = 0; ti < nt; ++ti) {
    const int kv = ti * 64;
    if (ti + 1 < nt) STAGE(cur ^ 1, kv + 64);

    const unsigned short* Kb = Ks[cur];
    const unsigned short* Vb = Vs[cur];
    unsigned short* pb_ = pbuf[w];

    // K and V fragments: loaded once, shared by all 4 q-sets
    s8v kf[8], vf[8];
#pragma unroll
    for (int sub = 0; sub < 4; sub++) {
      const char* krow = (const char*)Kb + (sub * 16 + lm) * 128;
      kf[sub * 2] = *(const s8v*)(krow + xo0);
      kf[sub * 2 + 1] = *(const s8v*)(krow + xo1);
      const char* vrow = (const char*)Vb + (sub * 16 + lm) * 128;
      vf[sub * 2] = *(const s8v*)(vrow + xo0);
      vf[sub * 2 + 1] = *(const s8v*)(vrow + xo1);
    }

    TILE_C(qf0, o0, m0_, l0_, q00);
    TILE_C(qf1, o1, m1_, l1_, q01);
    TILE_C(qf2, o2, m2_, l2_, q02);
    TILE_C(qf3, o3, m3_, l3_, q03);

    __syncthreads();
    cur ^= 1;
  }

  // epilogues
  const int b = bh >> 4, hh = bh & 15;
#define EPI(OO, LL, Q0)                                                         \
  {                                                                             \
    float lt = (LL);                                                            \
    lt += __shfl_xor(lt, 16);                                                   \
    lt += __shfl_xor(lt, 32);                                                   \
    const float inv = 1.f / lt;                                                 \
    unsigned short* Orow =                                                      \
        O + ((size_t)b * S_LEN + (Q0) + lm) * DMODEL + hh * HD;                 \
    _Pragma("unroll")                                                           \
    for (int nc = 0; nc < 4; nc++) {                                            \
      unsigned short h4[4];                                                     \
      _Pragma("unroll")                                                         \
      for (int rr = 0; rr < 4; rr++) h4[rr] = f2bf(OO[nc][rr] * inv);           \
      *(s4v*)(Orow + nc * 16 + lg * 4) = *(const s4v*)h4;                       \
    }                                                                           \
  }
  EPI(o0, l0_, q00);
  EPI(o1, l1_, q01);
  EPI(o2, l2_, q02);
  EPI(o3, l3_, q03);
#undef EPI
#undef TILE_C
#undef STAGE
}

extern "C" void kernel_launch(void* const* d_in, const int* in_sizes, int n_in,
                              void* d_out, int out_size, void* d_ws, size_t ws_size,
                              hipStream_t stream) {
  const float* queries = (const float*)d_in[0];
  const float* keys = (const float*)d_in[1];
  const float* values = (const float*)d_in[2];
  // d_in[3] = mask: constant causal tril -> handled analytically
  const float* Wq = (const float*)d_in[4];
  const float* Wk = (const float*)d_in[5];
  const float* Wv = (const float*)d_in[6];
  const float* Wo = (const float*)d_in[7];
  const float* bo = (const float*)d_in[8];

  char* ws = (char*)d_ws;
  const size_t WB = (size_t)DMODEL * DMODEL * 2;   // 2MB per weight
  unsigned short* WqT = (unsigned short*)(ws + 0 * WB);
  unsigned short* WkT = (unsigned short*)(ws + 1 * WB);
  unsigned short* WvT = (unsigned short*)(ws + 2 * WB);
  unsigned short* WoT = (unsigned short*)(ws + 3 * WB);
  const size_t TB = (size_t)4 * S_LEN * DMODEL * 2;  // 16MB per tensor
  unsigned short* Qb  = (unsigned short*)(ws + 4 * WB);
  unsigned short* Kb  = (unsigned short*)(ws + 4 * WB + TB);
  unsigned short* Vtb = (unsigned short*)(ws + 4 * WB + 2 * TB);
  unsigned short* Ob  = (unsigned short*)(ws + 4 * WB + 3 * TB);
  unsigned short* Qc  = (unsigned short*)(ws + 4 * WB + 4 * TB);  // bf16 casts
  unsigned short* Kc  = (unsigned short*)(ws + 4 * WB + 5 * TB);
  unsigned short* Vc  = (unsigned short*)(ws + 4 * WB + 6 * TB);

  const int M = 4 * S_LEN;  // 8192

  cast3<<<dim3(2048, 3), 256, 0, stream>>>(queries, keys, values, Qc, Kc, Vc,
                                           M * DMODEL / 8);

  dim3 tb(32, 8), tg(DMODEL / 32, DMODEL / 32);
  transpose_cast<<<tg, tb, 0, stream>>>(Wq, WqT, DMODEL, DMODEL);
  transpose_cast<<<tg, tb, 0, stream>>>(Wk, WkT, DMODEL, DMODEL);
  transpose_cast<<<tg, tb, 0, stream>>>(Wv, WvT, DMODEL, DMODEL);
  transpose_cast<<<tg, tb, 0, stream>>>(Wo, WoT, DMODEL, DMODEL);

  dim3 gg(DMODEL / 128, M / 128);  // (8, 64)
  gemm_k<1, false><<<gg, 256, 0, stream>>>(Qc, WqT, Qb, nullptr, M, DMODEL, DMODEL,
                                           0.125f * LOG2E);
  gemm_k<1, false><<<gg, 256, 0, stream>>>(Kc, WkT, Kb, nullptr, M, DMODEL, DMODEL, 1.0f);
  gemm_k<2, false><<<gg, 256, 0, stream>>>(Vc, WvT, Vtb, nullptr, M, DMODEL, DMODEL, 1.0f);

  attn_k<<<512, 256, 0, stream>>>(Qb, Kb, Vtb, Ob);

  gemm_k<0, true><<<gg, 256, 0, stream>>>(Ob, WoT, (float*)d_out, bo, M, DMODEL, DMODEL, 1.0f);
}